// Round 7
// baseline (920.323 us; speedup 1.0000x reference)
//
#include <hip/hip_runtime.h>

#define N_NODES  50000
#define NPAD     50048          // 782 * 64
#define IN_F     128
#define OUT_F    128
#define N_REL    8
#define N_BASES  4
#define N_EDGES  800000
#define E4       (N_EDGES / 4)  // 200000
#define KTOT     (N_REL * IN_F) // 1024
#define CAP      64             // fallback per-node bucket cap

// prep1 block-range split
#define G_HIST   2048           // 8 rel x 256
#define G_XB     6250           // N*IN_F/4/256
#define G_WS     512            // 128*1024/256

typedef unsigned short ushort_t;
typedef __attribute__((ext_vector_type(8))) short short8;
typedef __attribute__((ext_vector_type(4))) float f32x4;
typedef __attribute__((ext_vector_type(4))) int  int4v;

__device__ inline ushort_t f2bf(float f) {
    unsigned u = __float_as_uint(f);
    return (ushort_t)((u + 0x7fffu + ((u >> 16) & 1u)) >> 16);   // RNE
}
__device__ inline float bflo(unsigned v) { return __uint_as_float(v << 16); }
__device__ inline float bfhi(unsigned v) { return __uint_as_float(v & 0xffff0000u); }

__device__ inline void ws_body(const float* __restrict__ weight,
                               const float* __restrict__ w_comp,
                               ushort_t* __restrict__ BT, int idx)
{
    int o  = idx >> 10;
    int ri = idx & 1023;
    int r  = ri >> 7;
    int i  = ri & 127;
    float acc = 0.f;
#pragma unroll
    for (int b = 0; b < N_BASES; ++b)
        acc += w_comp[r * N_BASES + b] * weight[b * (IN_F * OUT_F) + i * OUT_F + o];
    BT[idx] = f2bf(acc);
}

// Fused prep: [0,G_HIST) dst histogram (XCD-sharded), [G_HIST,+G_XB) x->bf16,
// [..,+G_WS) basis-combined weights BT. Independent stages overlap on the CUs.
__global__ __launch_bounds__(256) void prep1_kernel(
    const float* __restrict__ weight,
    const float* __restrict__ w_comp,
    const float4* __restrict__ x4,
    const int4v* __restrict__ dst4,
    ushort_t* __restrict__ BT,
    uint2* __restrict__ xb,
    int* __restrict__ cnt)
{
    int bid = blockIdx.x;
    if (bid < G_HIST) {
        int r  = bid & 7;
        int cb = bid >> 3;                            // 0..255
        const int4v* d4 = dst4 + (size_t)r * E4;
        int base = r * N_NODES;
        for (int i = cb * 256 + (int)threadIdx.x; i < E4; i += 256 * 256) {
            int4v d = __builtin_nontemporal_load(&d4[i]);
            atomicAdd(&cnt[base + d.x], 1);
            atomicAdd(&cnt[base + d.y], 1);
            atomicAdd(&cnt[base + d.z], 1);
            atomicAdd(&cnt[base + d.w], 1);
        }
    } else if (bid < G_HIST + G_XB) {
        int i = (bid - G_HIST) * 256 + threadIdx.x;   // over N*IN_F/4
        float4 v = x4[i];
        uint2 p;
        p.x = (unsigned)f2bf(v.x) | ((unsigned)f2bf(v.y) << 16);
        p.y = (unsigned)f2bf(v.z) | ((unsigned)f2bf(v.w) << 16);
        xb[i] = p;
    } else {
        ws_body(weight, w_comp, BT, (bid - G_HIST - G_XB) * 256 + threadIdx.x);
    }
}

// Standalone ws kernel (fallback path)
__global__ __launch_bounds__(256) void ws_only_kernel(
    const float* __restrict__ weight,
    const float* __restrict__ w_comp,
    ushort_t* __restrict__ BT)
{
    ws_body(weight, w_comp, BT, blockIdx.x * 256 + threadIdx.x);
}

// Exclusive scan of cnt -> start, one block per relation, wave-shuffle scan.
__global__ __launch_bounds__(1024) void scan_kernel(
    const int* __restrict__ cnt, int* __restrict__ start)
{
    __shared__ int swv[16];
    int r = blockIdx.x;
    int tid = threadIdx.x;
    int lane = tid & 63, wid = tid >> 6;
    int rN = r * N_NODES;
    int carry = 0;
    for (int chunk = 0; chunk < N_NODES; chunk += 1024) {
        int n = chunk + tid;
        int v = (n < N_NODES) ? cnt[rN + n] : 0;
        int inc = v;
#pragma unroll
        for (int off = 1; off < 64; off <<= 1) {
            int t = __shfl_up(inc, off);
            if (lane >= off) inc += t;
        }
        if (lane == 63) swv[wid] = inc;
        __syncthreads();
        if (tid < 16) {
            int iw = swv[tid];
#pragma unroll
            for (int off = 1; off < 16; off <<= 1) {
                int t = __shfl_up(iw, off, 16);
                if (tid >= off) iw += t;
            }
            swv[tid] = iw;                            // inclusive wave-sums
        }
        __syncthreads();
        int base = (wid == 0) ? 0 : swv[wid - 1];
        if (n < N_NODES) start[rN + n] = carry + base + inc - v;
        int total = swv[15];
        __syncthreads();
        carry += total;
    }
}

// Place src ids into compact CSR. atomicAdd on start[] itself: returned old
// value is the slot; post-kernel start[sl] == end offset of node sl.
__global__ __launch_bounds__(256) void place_kernel(
    const int4v* __restrict__ src4,
    const int4v* __restrict__ dst4,
    int* __restrict__ start,
    ushort_t* __restrict__ earr)
{
    int r  = blockIdx.x & 7;
    int cb = blockIdx.x >> 3;
    const int4v* s4 = src4 + (size_t)r * E4;
    const int4v* d4 = dst4 + (size_t)r * E4;
    int base = r * N_NODES;
    ushort_t* er = earr + (size_t)r * N_EDGES;
    for (int i = cb * 256 + (int)threadIdx.x; i < E4; i += 256 * 256) {
        int4v s = __builtin_nontemporal_load(&s4[i]);
        int4v d = __builtin_nontemporal_load(&d4[i]);
#define PUT(DV, SV) { int pos = atomicAdd(&start[base + (DV)], 1);            \
        er[pos] = (ushort_t)(SV); }
        PUT(d.x, s.x) PUT(d.y, s.y) PUT(d.z, s.z) PUT(d.w, s.w)
#undef PUT
    }
}

// One wave per (relation, node); begin = end - cnt (start[] holds ends now).
// 4-deep gather pipeline over 256B bf16 rows of xb.
__global__ __launch_bounds__(256) void gather_csr_kernel(
    const unsigned* __restrict__ xb,   // [N][64] dwords
    const int* __restrict__ cnt,
    const int* __restrict__ start,
    const ushort_t* __restrict__ earr,
    ushort_t* __restrict__ A)          // [NPAD][KTOT]
{
    int r = blockIdx.x & 7;
    int n = (blockIdx.x >> 3) * 4 + ((int)threadIdx.x >> 6);
    int lane = threadIdx.x & 63;
    int slot = r * N_NODES + n;
    int c = cnt[slot];
    const ushort_t* ep = earr + (size_t)r * N_EDGES + (start[slot] - c);

    float ax = 0.f, ay = 0.f, bx = 0.f, by = 0.f;
    for (int base = 0; base < c; base += 64) {
        int m = min(c - base, 64);
        int sid = (lane < m) ? (int)ep[base + lane] : 0;
        int e = 0;
        for (; e + 4 <= m; e += 4) {
            int s0 = __shfl(sid, e);
            int s1 = __shfl(sid, e + 1);
            int s2 = __shfl(sid, e + 2);
            int s3 = __shfl(sid, e + 3);
            unsigned v0 = xb[(size_t)s0 * 64 + lane];
            unsigned v1 = xb[(size_t)s1 * 64 + lane];
            unsigned v2 = xb[(size_t)s2 * 64 + lane];
            unsigned v3 = xb[(size_t)s3 * 64 + lane];
            ax += bflo(v0); ay += bfhi(v0);
            bx += bflo(v1); by += bfhi(v1);
            ax += bflo(v2); ay += bfhi(v2);
            bx += bflo(v3); by += bfhi(v3);
        }
        for (; e < m; ++e) {
            int s0 = __shfl(sid, e);
            unsigned v0 = xb[(size_t)s0 * 64 + lane];
            ax += bflo(v0); ay += bfhi(v0);
        }
    }
    const float inv = 1.0f / fmaxf((float)c, 1.0f);
    unsigned lo = f2bf((ax + bx) * inv);
    unsigned hi = f2bf((ay + by) * inv);
    ((unsigned*)(A + (size_t)n * KTOT + r * IN_F))[lane] = lo | (hi << 16);
}

// ---------------- fallback-path kernels (small workspace) ----------------
__global__ __launch_bounds__(256) void bucket_fill_kernel(
    const int* __restrict__ src,
    const int* __restrict__ dst,
    int* __restrict__ cnt,
    ushort_t* __restrict__ bucket,
    int nedges)
{
    int e = blockIdx.x * 256 + threadIdx.x;
    if (e >= nedges) return;
    int d = dst[e];
    int pos = atomicAdd(&cnt[d], 1);
    if (pos < CAP)
        bucket[(size_t)d * CAP + pos] = (ushort_t)src[e];
}

__global__ __launch_bounds__(256) void gather_mean_fb_kernel(
    const float* __restrict__ x,
    const int* __restrict__ cnt,
    const ushort_t* __restrict__ bucket,
    ushort_t* __restrict__ A)
{
    int wv = (blockIdx.x * 256 + threadIdx.x) >> 6;
    if (wv >= N_NODES) return;
    int lane = threadIdx.x & 63;
    int c  = cnt[wv];
    int cc = min(c, CAP);
    int sid = (lane < cc) ? (int)bucket[(size_t)wv * CAP + lane] : 0;

    float ax = 0.f, ay = 0.f, bx = 0.f, by = 0.f;
    int e = 0;
    for (; e + 2 <= cc; e += 2) {
        int s0 = __shfl(sid, e);
        int s1 = __shfl(sid, e + 1);
        const float2 v0 = *(const float2*)(x + (size_t)s0 * IN_F + lane * 2);
        const float2 v1 = *(const float2*)(x + (size_t)s1 * IN_F + lane * 2);
        ax += v0.x; ay += v0.y;
        bx += v1.x; by += v1.y;
    }
    if (e < cc) {
        int s0 = __shfl(sid, e);
        const float2 v0 = *(const float2*)(x + (size_t)s0 * IN_F + lane * 2);
        ax += v0.x; ay += v0.y;
    }
    const float inv = 1.0f / fmaxf((float)c, 1.0f);
    unsigned lo = f2bf((ax + bx) * inv);
    unsigned hi = f2bf((ay + by) * inv);
    ((unsigned*)(A + (size_t)wv * IN_F))[lane] = lo | (hi << 16);
}

// C[rows x 128] (+)= A[rows x K]_bf16 @ B (BT stored [128][KTOT]).
// Block 256 = 4 waves; tile 64 rows x 128 cols; wave = 32 rows x 64 cols.
// Compile-time K, register double-buffer prefetch, nontemporal A loads.
template <int K, int LDA>
__global__ __launch_bounds__(256) void gemm_mfma_kernel(
    const ushort_t* __restrict__ A,
    const ushort_t* __restrict__ BT, int kbase,
    float* __restrict__ out, const float* __restrict__ bias,
    int first, int last)
{
    int tid  = threadIdx.x;
    int wave = tid >> 6, lane = tid & 63;
    int rowf = lane & 15, kg = lane >> 4;
    int rbase = blockIdx.x * 64 + (wave & 1) * 32;
    int cbase = (wave >> 1) * 64;

    f32x4 acc[2][4];
#pragma unroll
    for (int t = 0; t < 2; ++t)
#pragma unroll
        for (int c = 0; c < 4; ++c) acc[t][c] = (f32x4){0.f, 0.f, 0.f, 0.f};

    const short8* Ar0 = (const short8*)(A + (size_t)(rbase + rowf) * LDA + kg * 8);
    const short8* Ar1 = (const short8*)(A + (size_t)(rbase + 16 + rowf) * LDA + kg * 8);
    const ushort_t* Bb = BT + (size_t)(cbase + rowf) * KTOT + kbase + kg * 8;

    short8 a0 = __builtin_nontemporal_load(Ar0);
    short8 a1 = __builtin_nontemporal_load(Ar1);
    short8 b0 = *(const short8*)(Bb);
    short8 b1 = *(const short8*)(Bb + 16 * KTOT);
    short8 b2 = *(const short8*)(Bb + 32 * KTOT);
    short8 b3 = *(const short8*)(Bb + 48 * KTOT);

#pragma unroll
    for (int k0 = 0; k0 < K; k0 += 32) {
        short8 na0 = a0, na1 = a1, nb0 = b0, nb1 = b1, nb2 = b2, nb3 = b3;
        if (k0 + 32 < K) {
            int kk = (k0 + 32) / 8;                   // in short8 units
            na0 = __builtin_nontemporal_load(Ar0 + kk);
            na1 = __builtin_nontemporal_load(Ar1 + kk);
            nb0 = *(const short8*)(Bb + k0 + 32);
            nb1 = *(const short8*)(Bb + 16 * KTOT + k0 + 32);
            nb2 = *(const short8*)(Bb + 32 * KTOT + k0 + 32);
            nb3 = *(const short8*)(Bb + 48 * KTOT + k0 + 32);
        }
        acc[0][0] = __builtin_amdgcn_mfma_f32_16x16x32_bf16(a0, b0, acc[0][0], 0, 0, 0);
        acc[1][0] = __builtin_amdgcn_mfma_f32_16x16x32_bf16(a1, b0, acc[1][0], 0, 0, 0);
        acc[0][1] = __builtin_amdgcn_mfma_f32_16x16x32_bf16(a0, b1, acc[0][1], 0, 0, 0);
        acc[1][1] = __builtin_amdgcn_mfma_f32_16x16x32_bf16(a1, b1, acc[1][1], 0, 0, 0);
        acc[0][2] = __builtin_amdgcn_mfma_f32_16x16x32_bf16(a0, b2, acc[0][2], 0, 0, 0);
        acc[1][2] = __builtin_amdgcn_mfma_f32_16x16x32_bf16(a1, b2, acc[1][2], 0, 0, 0);
        acc[0][3] = __builtin_amdgcn_mfma_f32_16x16x32_bf16(a0, b3, acc[0][3], 0, 0, 0);
        acc[1][3] = __builtin_amdgcn_mfma_f32_16x16x32_bf16(a1, b3, acc[1][3], 0, 0, 0);
        a0 = na0; a1 = na1; b0 = nb0; b1 = nb1; b2 = nb2; b3 = nb3;
    }

    // C/D layout: col = lane&15, row = (lane>>4)*4 + j
#pragma unroll
    for (int t = 0; t < 2; ++t) {
#pragma unroll
        for (int c = 0; c < 4; ++c) {
            int col = cbase + c * 16 + rowf;
#pragma unroll
            for (int j = 0; j < 4; ++j) {
                int row = rbase + t * 16 + kg * 4 + j;
                if (row < N_NODES) {
                    float v = acc[t][c][j];
                    float* p = out + (size_t)row * OUT_F + col;
                    if (!first) v += *p;
                    if (last)  v = fmaxf(v + bias[col], 0.f);
                    *p = v;
                }
            }
        }
    }
}

extern "C" void kernel_launch(void* const* d_in, const int* in_sizes, int n_in,
                              void* d_out, int out_size, void* d_ws, size_t ws_size,
                              hipStream_t stream) {
    const float* x      = (const float*)d_in[0];
    const float* weight = (const float*)d_in[1];
    const float* w_comp = (const float*)d_in[2];
    const float* h_bias = (const float*)d_in[3];
    const int*   src    = (const int*)d_in[4];
    const int*   dst    = (const int*)d_in[5];
    float* out = (float*)d_out;

    char* wsb = (char*)d_ws;
    const size_t btSz   = (size_t)OUT_F * KTOT * 2;            // 256 KB
    const size_t cntSz  = (size_t)N_REL * N_NODES * 4;         // 1.6 MB
    const size_t earrSz = (size_t)N_REL * N_EDGES * 2;         // 12.8 MB
    const size_t aSz    = (size_t)NPAD * KTOT * 2;             // 102.5 MB
    const size_t xbSz   = (size_t)N_NODES * 64 * 4;            // 12.8 MB
    const size_t need   = btSz + 2 * cntSz + earrSz + aSz + xbSz; // ~131.5 MB

    ushort_t* BT = (ushort_t*)wsb;

    if (ws_size >= need) {
        int*      cnt   = (int*)(wsb + btSz);
        int*      start = (int*)(wsb + btSz + cntSz);
        ushort_t* earr  = (ushort_t*)(wsb + btSz + 2 * cntSz);
        ushort_t* A     = (ushort_t*)(wsb + btSz + 2 * cntSz + earrSz);
        unsigned* xb    = (unsigned*)(wsb + btSz + 2 * cntSz + earrSz + aSz);

        hipMemsetAsync(cnt, 0, cntSz, stream);
        prep1_kernel<<<G_HIST + G_XB + G_WS, 256, 0, stream>>>(
            weight, w_comp, (const float4*)x, (const int4v*)dst,
            BT, (uint2*)xb, cnt);
        scan_kernel<<<N_REL, 1024, 0, stream>>>(cnt, start);
        place_kernel<<<8 * 256, 256, 0, stream>>>(
            (const int4v*)src, (const int4v*)dst, start, earr);
        gather_csr_kernel<<<8 * (N_NODES / 4), 256, 0, stream>>>(
            xb, cnt, start, earr, A);
        gemm_mfma_kernel<KTOT, KTOT><<<NPAD / 64, 256, 0, stream>>>(
            A, BT, 0, out, h_bias, 1, 1);
    } else {
        // per-relation fallback (~19.7 MB)
        const size_t cntSz1 = (size_t)N_NODES * 4;
        const size_t bktSz1 = (size_t)N_NODES * CAP * 2;
        int*      cnt    = (int*)(wsb + btSz);
        ushort_t* bucket = (ushort_t*)(wsb + btSz + cntSz1);
        ushort_t* A      = (ushort_t*)(wsb + btSz + cntSz1 + bktSz1);

        ws_only_kernel<<<G_WS, 256, 0, stream>>>(weight, w_comp, BT);
        for (int r = 0; r < N_REL; ++r) {
            hipMemsetAsync(cnt, 0, cntSz1, stream);
            bucket_fill_kernel<<<(N_EDGES + 255) / 256, 256, 0, stream>>>(
                src + (size_t)r * N_EDGES, dst + (size_t)r * N_EDGES,
                cnt, bucket, N_EDGES);
            gather_mean_fb_kernel<<<(N_NODES * 64 + 255) / 256, 256, 0, stream>>>(
                x, cnt, bucket, A);
            gemm_mfma_kernel<IN_F, IN_F><<<NPAD / 64, 256, 0, stream>>>(
                A, BT, r * IN_F, out, h_bias, r == 0, r == N_REL - 1);
        }
    }
}

// Round 8
// 615.435 us; speedup vs baseline: 1.4954x; 1.4954x over previous
//
#include <hip/hip_runtime.h>

#define N_NODES  50000
#define NPAD     50048          // 782 * 64
#define IN_F     128
#define OUT_F    128
#define N_REL    8
#define N_BASES  4
#define N_EDGES  800000
#define E4       (N_EDGES / 4)  // 200000
#define KTOT     (N_REL * IN_F) // 1024
#define CAP      64             // fallback per-node bucket cap
#define NBIN     782            // bins of 64 nodes per relation
#define BINCAP   1280           // Poisson(1024): mu + 8 sigma

// prep_fused block-range split
#define G_BIN    2048           // 8 rel x 256
#define G_XB     6250           // N*IN_F/4/256
#define G_WS     512            // 128*1024/256

typedef unsigned short ushort_t;
typedef __attribute__((ext_vector_type(8))) short short8;
typedef __attribute__((ext_vector_type(4))) float f32x4;
typedef __attribute__((ext_vector_type(4))) int  int4v;

__device__ inline ushort_t f2bf(float f) {
    unsigned u = __float_as_uint(f);
    return (ushort_t)((u + 0x7fffu + ((u >> 16) & 1u)) >> 16);   // RNE
}
__device__ inline float bflo(unsigned v) { return __uint_as_float(v << 16); }
__device__ inline float bfhi(unsigned v) { return __uint_as_float(v & 0xffff0000u); }

__device__ inline void ws_body(const float* __restrict__ weight,
                               const float* __restrict__ w_comp,
                               ushort_t* __restrict__ BT, int idx)
{
    int o  = idx >> 10;
    int ri = idx & 1023;
    int r  = ri >> 7;
    int i  = ri & 127;
    float acc = 0.f;
#pragma unroll
    for (int b = 0; b < N_BASES; ++b)
        acc += w_comp[r * N_BASES + b] * weight[b * (IN_F * OUT_F) + i * OUT_F + o];
    BT[idx] = f2bf(acc);
}

// Fused prep: [0,G_BIN) edge append into coarse bins (XCD-sharded),
// [G_BIN,+G_XB) x->bf16, [..,+G_WS) basis-combined weights BT.
// Bin appends are SEQUENTIAL per bin -> full-line writebacks (the R3/R4/R7
// scatter-store amplification is structurally impossible here).
__global__ __launch_bounds__(256) void prep_fused_kernel(
    const float* __restrict__ weight,
    const float* __restrict__ w_comp,
    const float4* __restrict__ x4,
    const int4v* __restrict__ src4,
    const int4v* __restrict__ dst4,
    ushort_t* __restrict__ BT,
    uint2* __restrict__ xb,
    int* __restrict__ btail,           // stride 16 ints per bin (64B line)
    unsigned* __restrict__ binbuf)
{
    int bid = blockIdx.x;
    if (bid < G_BIN) {
        int r  = bid & 7;
        int cb = bid >> 3;                            // 0..255
        const int4v* s4 = src4 + (size_t)r * E4;
        const int4v* d4 = dst4 + (size_t)r * E4;
        int b0 = r * NBIN;
        for (int i = cb * 256 + (int)threadIdx.x; i < E4; i += 256 * 256) {
            int4v s = __builtin_nontemporal_load(&s4[i]);
            int4v d = __builtin_nontemporal_load(&d4[i]);
#define PUT(DV, SV) { int b = b0 + ((DV) >> 6);                               \
        int pos = atomicAdd(&btail[b * 16], 1);                               \
        if (pos < BINCAP)                                                     \
            binbuf[(size_t)b * BINCAP + pos] =                                \
                (unsigned)(SV) | ((unsigned)((DV) & 63) << 16); }
            PUT(d.x, s.x) PUT(d.y, s.y) PUT(d.z, s.z) PUT(d.w, s.w)
#undef PUT
        }
    } else if (bid < G_BIN + G_XB) {
        int i = (bid - G_BIN) * 256 + threadIdx.x;    // over N*IN_F/4 exact
        float4 v = x4[i];
        uint2 p;
        p.x = (unsigned)f2bf(v.x) | ((unsigned)f2bf(v.y) << 16);
        p.y = (unsigned)f2bf(v.z) | ((unsigned)f2bf(v.w) << 16);
        xb[i] = p;
    } else {
        ws_body(weight, w_comp, BT, (bid - G_BIN - G_XB) * 256 + threadIdx.x);
    }
}

// Standalone ws kernel (fallback path)
__global__ __launch_bounds__(256) void ws_only_kernel(
    const float* __restrict__ weight,
    const float* __restrict__ w_comp,
    ushort_t* __restrict__ BT)
{
    ws_body(weight, w_comp, BT, blockIdx.x * 256 + threadIdx.x);
}

// Exclusive scan of clamped bin totals -> binbase. One block per relation;
// base offset r*N_EDGES keeps relations in disjoint earr regions.
__global__ __launch_bounds__(256) void scan_bins_kernel(
    const int* __restrict__ btail, int* __restrict__ binbase)
{
    __shared__ int swv[4];
    int r = blockIdx.x;
    int tid = threadIdx.x;
    int lane = tid & 63, wid = tid >> 6;
    int carry = 0;
    for (int chunk = 0; chunk < NBIN; chunk += 256) {
        int i = chunk + tid;
        int v = (i < NBIN) ? min(btail[(r * NBIN + i) * 16], BINCAP) : 0;
        int inc = v;
#pragma unroll
        for (int off = 1; off < 64; off <<= 1) {
            int t = __shfl_up(inc, off);
            if (lane >= off) inc += t;
        }
        if (lane == 63) swv[wid] = inc;
        __syncthreads();
        if (tid < 4) {
            int iw = swv[tid];
#pragma unroll
            for (int off = 1; off < 4; off <<= 1) {
                int t = __shfl_up(iw, off, 4);
                if (tid >= off) iw += t;
            }
            swv[tid] = iw;
        }
        __syncthreads();
        int base = (wid == 0) ? 0 : swv[wid - 1];
        if (i < NBIN)
            binbase[r * NBIN + i] = r * N_EDGES + carry + base + inc - v;
        int total = swv[3];
        __syncthreads();
        carry += total;
    }
}

// One block per bin: LDS histogram (writes cnt/start for the gather), LDS
// counting-sort, then CONTIGUOUS stream of the sorted window into earr.
__global__ __launch_bounds__(256) void bin_sort_kernel(
    const int* __restrict__ btail,
    const unsigned* __restrict__ binbuf,
    const int* __restrict__ binbase,
    int* __restrict__ cnt,
    int* __restrict__ start,
    ushort_t* __restrict__ earr)
{
    __shared__ unsigned ent[BINCAP];   // 5 KB
    __shared__ ushort_t srt[BINCAP];   // 2.5 KB
    __shared__ int h[64], scur[64];

    int gb = blockIdx.x;               // r*NBIN + bin
    int r  = gb / NBIN;
    int bin = gb - r * NBIN;
    int t = threadIdx.x;
    int cb = min(btail[gb * 16], BINCAP);
    int base = binbase[gb];

    if (t < 64) h[t] = 0;
    __syncthreads();
    for (int i = t; i < cb; i += 256) {
        unsigned e = binbuf[(size_t)gb * BINCAP + i];
        ent[i] = e;
        atomicAdd(&h[e >> 16], 1);
    }
    __syncthreads();
    if (t < 64) {                      // wave 0: scan 64 node counts
        int v = h[t];
        int inc = v;
#pragma unroll
        for (int off = 1; off < 64; off <<= 1) {
            int u = __shfl_up(inc, off);
            if (t >= off) inc += u;
        }
        int excl = inc - v;
        scur[t] = excl;
        int gn = bin * 64 + t;
        if (gn < N_NODES) {
            cnt[r * N_NODES + gn]   = v;
            start[r * N_NODES + gn] = base + excl;
        }
    }
    __syncthreads();
    for (int i = t; i < cb; i += 256) {
        unsigned e = ent[i];
        int p = atomicAdd(&scur[e >> 16], 1);
        srt[p] = (ushort_t)(e & 0xFFFFu);
    }
    __syncthreads();
    for (int i = t; i < cb; i += 256)
        earr[base + i] = srt[i];
}

// One wave per (relation, node). start[] = begin offset (absolute in earr).
// 4-deep gather pipeline over 256B bf16 rows of xb.
__global__ __launch_bounds__(256) void gather_csr_kernel(
    const unsigned* __restrict__ xb,   // [N][64] dwords
    const int* __restrict__ cnt,
    const int* __restrict__ start,
    const ushort_t* __restrict__ earr,
    ushort_t* __restrict__ A)          // [NPAD][KTOT]
{
    int r = blockIdx.x & 7;
    int n = (blockIdx.x >> 3) * 4 + ((int)threadIdx.x >> 6);
    int lane = threadIdx.x & 63;
    int slot = r * N_NODES + n;
    int c = cnt[slot];
    const ushort_t* ep = earr + start[slot];

    float ax = 0.f, ay = 0.f, bx = 0.f, by = 0.f;
    for (int base = 0; base < c; base += 64) {
        int m = min(c - base, 64);
        int sid = (lane < m) ? (int)ep[base + lane] : 0;
        int e = 0;
        for (; e + 4 <= m; e += 4) {
            int s0 = __shfl(sid, e);
            int s1 = __shfl(sid, e + 1);
            int s2 = __shfl(sid, e + 2);
            int s3 = __shfl(sid, e + 3);
            unsigned v0 = xb[(size_t)s0 * 64 + lane];
            unsigned v1 = xb[(size_t)s1 * 64 + lane];
            unsigned v2 = xb[(size_t)s2 * 64 + lane];
            unsigned v3 = xb[(size_t)s3 * 64 + lane];
            ax += bflo(v0); ay += bfhi(v0);
            bx += bflo(v1); by += bfhi(v1);
            ax += bflo(v2); ay += bfhi(v2);
            bx += bflo(v3); by += bfhi(v3);
        }
        for (; e < m; ++e) {
            int s0 = __shfl(sid, e);
            unsigned v0 = xb[(size_t)s0 * 64 + lane];
            ax += bflo(v0); ay += bfhi(v0);
        }
    }
    const float inv = 1.0f / fmaxf((float)c, 1.0f);
    unsigned lo = f2bf((ax + bx) * inv);
    unsigned hi = f2bf((ay + by) * inv);
    ((unsigned*)(A + (size_t)n * KTOT + r * IN_F))[lane] = lo | (hi << 16);
}

// ---------------- fallback-path kernels (small workspace) ----------------
__global__ __launch_bounds__(256) void bucket_fill_kernel(
    const int* __restrict__ src,
    const int* __restrict__ dst,
    int* __restrict__ cnt,
    ushort_t* __restrict__ bucket,
    int nedges)
{
    int e = blockIdx.x * 256 + threadIdx.x;
    if (e >= nedges) return;
    int d = dst[e];
    int pos = atomicAdd(&cnt[d], 1);
    if (pos < CAP)
        bucket[(size_t)d * CAP + pos] = (ushort_t)src[e];
}

__global__ __launch_bounds__(256) void gather_mean_fb_kernel(
    const float* __restrict__ x,
    const int* __restrict__ cnt,
    const ushort_t* __restrict__ bucket,
    ushort_t* __restrict__ A)
{
    int wv = (blockIdx.x * 256 + threadIdx.x) >> 6;
    if (wv >= N_NODES) return;
    int lane = threadIdx.x & 63;
    int c  = cnt[wv];
    int cc = min(c, CAP);
    int sid = (lane < cc) ? (int)bucket[(size_t)wv * CAP + lane] : 0;

    float ax = 0.f, ay = 0.f, bx = 0.f, by = 0.f;
    int e = 0;
    for (; e + 2 <= cc; e += 2) {
        int s0 = __shfl(sid, e);
        int s1 = __shfl(sid, e + 1);
        const float2 v0 = *(const float2*)(x + (size_t)s0 * IN_F + lane * 2);
        const float2 v1 = *(const float2*)(x + (size_t)s1 * IN_F + lane * 2);
        ax += v0.x; ay += v0.y;
        bx += v1.x; by += v1.y;
    }
    if (e < cc) {
        int s0 = __shfl(sid, e);
        const float2 v0 = *(const float2*)(x + (size_t)s0 * IN_F + lane * 2);
        ax += v0.x; ay += v0.y;
    }
    const float inv = 1.0f / fmaxf((float)c, 1.0f);
    unsigned lo = f2bf((ax + bx) * inv);
    unsigned hi = f2bf((ay + by) * inv);
    ((unsigned*)(A + (size_t)wv * IN_F))[lane] = lo | (hi << 16);
}

// C[rows x 128] (+)= A[rows x K]_bf16 @ B (BT stored [128][KTOT]).
// Block 256 = 4 waves; tile 64 rows x 128 cols; wave = 32 rows x 64 cols.
// Compile-time K, register double-buffer prefetch, nontemporal A loads.
template <int K, int LDA>
__global__ __launch_bounds__(256) void gemm_mfma_kernel(
    const ushort_t* __restrict__ A,
    const ushort_t* __restrict__ BT, int kbase,
    float* __restrict__ out, const float* __restrict__ bias,
    int first, int last)
{
    int tid  = threadIdx.x;
    int wave = tid >> 6, lane = tid & 63;
    int rowf = lane & 15, kg = lane >> 4;
    int rbase = blockIdx.x * 64 + (wave & 1) * 32;
    int cbase = (wave >> 1) * 64;

    f32x4 acc[2][4];
#pragma unroll
    for (int t = 0; t < 2; ++t)
#pragma unroll
        for (int c = 0; c < 4; ++c) acc[t][c] = (f32x4){0.f, 0.f, 0.f, 0.f};

    const short8* Ar0 = (const short8*)(A + (size_t)(rbase + rowf) * LDA + kg * 8);
    const short8* Ar1 = (const short8*)(A + (size_t)(rbase + 16 + rowf) * LDA + kg * 8);
    const ushort_t* Bb = BT + (size_t)(cbase + rowf) * KTOT + kbase + kg * 8;

    short8 a0 = __builtin_nontemporal_load(Ar0);
    short8 a1 = __builtin_nontemporal_load(Ar1);
    short8 b0 = *(const short8*)(Bb);
    short8 b1 = *(const short8*)(Bb + 16 * KTOT);
    short8 b2 = *(const short8*)(Bb + 32 * KTOT);
    short8 b3 = *(const short8*)(Bb + 48 * KTOT);

#pragma unroll
    for (int k0 = 0; k0 < K; k0 += 32) {
        short8 na0 = a0, na1 = a1, nb0 = b0, nb1 = b1, nb2 = b2, nb3 = b3;
        if (k0 + 32 < K) {
            int kk = (k0 + 32) / 8;                   // in short8 units
            na0 = __builtin_nontemporal_load(Ar0 + kk);
            na1 = __builtin_nontemporal_load(Ar1 + kk);
            nb0 = *(const short8*)(Bb + k0 + 32);
            nb1 = *(const short8*)(Bb + 16 * KTOT + k0 + 32);
            nb2 = *(const short8*)(Bb + 32 * KTOT + k0 + 32);
            nb3 = *(const short8*)(Bb + 48 * KTOT + k0 + 32);
        }
        acc[0][0] = __builtin_amdgcn_mfma_f32_16x16x32_bf16(a0, b0, acc[0][0], 0, 0, 0);
        acc[1][0] = __builtin_amdgcn_mfma_f32_16x16x32_bf16(a1, b0, acc[1][0], 0, 0, 0);
        acc[0][1] = __builtin_amdgcn_mfma_f32_16x16x32_bf16(a0, b1, acc[0][1], 0, 0, 0);
        acc[1][1] = __builtin_amdgcn_mfma_f32_16x16x32_bf16(a1, b1, acc[1][1], 0, 0, 0);
        acc[0][2] = __builtin_amdgcn_mfma_f32_16x16x32_bf16(a0, b2, acc[0][2], 0, 0, 0);
        acc[1][2] = __builtin_amdgcn_mfma_f32_16x16x32_bf16(a1, b2, acc[1][2], 0, 0, 0);
        acc[0][3] = __builtin_amdgcn_mfma_f32_16x16x32_bf16(a0, b3, acc[0][3], 0, 0, 0);
        acc[1][3] = __builtin_amdgcn_mfma_f32_16x16x32_bf16(a1, b3, acc[1][3], 0, 0, 0);
        a0 = na0; a1 = na1; b0 = nb0; b1 = nb1; b2 = nb2; b3 = nb3;
    }

    // C/D layout: col = lane&15, row = (lane>>4)*4 + j
#pragma unroll
    for (int t = 0; t < 2; ++t) {
#pragma unroll
        for (int c = 0; c < 4; ++c) {
            int col = cbase + c * 16 + rowf;
#pragma unroll
            for (int j = 0; j < 4; ++j) {
                int row = rbase + t * 16 + kg * 4 + j;
                if (row < N_NODES) {
                    float v = acc[t][c][j];
                    float* p = out + (size_t)row * OUT_F + col;
                    if (!first) v += *p;
                    if (last)  v = fmaxf(v + bias[col], 0.f);
                    *p = v;
                }
            }
        }
    }
}

extern "C" void kernel_launch(void* const* d_in, const int* in_sizes, int n_in,
                              void* d_out, int out_size, void* d_ws, size_t ws_size,
                              hipStream_t stream) {
    const float* x      = (const float*)d_in[0];
    const float* weight = (const float*)d_in[1];
    const float* w_comp = (const float*)d_in[2];
    const float* h_bias = (const float*)d_in[3];
    const int*   src    = (const int*)d_in[4];
    const int*   dst    = (const int*)d_in[5];
    float* out = (float*)d_out;

    char* wsb = (char*)d_ws;
    const size_t btSz    = (size_t)OUT_F * KTOT * 2;               // 256 KB
    const size_t btailSz = (size_t)N_REL * NBIN * 16 * 4;          // 400 KB
    const size_t bbufSz  = (size_t)N_REL * NBIN * BINCAP * 4;      // 32.0 MB
    const size_t bbaseSz = (size_t)((N_REL * NBIN * 4 + 255) & ~255); // ~25 KB
    const size_t cntSz   = (size_t)N_REL * N_NODES * 4;            // 1.6 MB
    const size_t earrSz  = (size_t)N_REL * N_EDGES * 2;            // 12.8 MB
    const size_t aSz     = (size_t)NPAD * KTOT * 2;                // 102.5 MB
    const size_t xbSz    = (size_t)N_NODES * 64 * 4;               // 12.8 MB
    const size_t need    = btSz + btailSz + bbufSz + bbaseSz
                         + 2 * cntSz + earrSz + aSz + xbSz;        // ~164 MB

    ushort_t* BT = (ushort_t*)wsb;

    if (ws_size >= need) {
        size_t off = btSz;
        int*      btail   = (int*)(wsb + off);      off += btailSz;
        unsigned* binbuf  = (unsigned*)(wsb + off); off += bbufSz;
        int*      binbase = (int*)(wsb + off);      off += bbaseSz;
        int*      cnt     = (int*)(wsb + off);      off += cntSz;
        int*      start   = (int*)(wsb + off);      off += cntSz;
        ushort_t* earr    = (ushort_t*)(wsb + off); off += earrSz;
        ushort_t* A       = (ushort_t*)(wsb + off); off += aSz;
        unsigned* xb      = (unsigned*)(wsb + off);

        hipMemsetAsync(btail, 0, btailSz, stream);
        prep_fused_kernel<<<G_BIN + G_XB + G_WS, 256, 0, stream>>>(
            weight, w_comp, (const float4*)x, (const int4v*)src,
            (const int4v*)dst, BT, (uint2*)xb, btail, binbuf);
        scan_bins_kernel<<<N_REL, 256, 0, stream>>>(btail, binbase);
        bin_sort_kernel<<<N_REL * NBIN, 256, 0, stream>>>(
            btail, binbuf, binbase, cnt, start, earr);
        gather_csr_kernel<<<8 * (N_NODES / 4), 256, 0, stream>>>(
            xb, cnt, start, earr, A);
        gemm_mfma_kernel<KTOT, KTOT><<<NPAD / 64, 256, 0, stream>>>(
            A, BT, 0, out, h_bias, 1, 1);
    } else {
        // per-relation fallback (~19.7 MB)
        const size_t cntSz1 = (size_t)N_NODES * 4;
        const size_t bktSz1 = (size_t)N_NODES * CAP * 2;
        int*      cnt    = (int*)(wsb + btSz);
        ushort_t* bucket = (ushort_t*)(wsb + btSz + cntSz1);
        ushort_t* A      = (ushort_t*)(wsb + btSz + cntSz1 + bktSz1);

        ws_only_kernel<<<G_WS, 256, 0, stream>>>(weight, w_comp, BT);
        for (int r = 0; r < N_REL; ++r) {
            hipMemsetAsync(cnt, 0, cntSz1, stream);
            bucket_fill_kernel<<<(N_EDGES + 255) / 256, 256, 0, stream>>>(
                src + (size_t)r * N_EDGES, dst + (size_t)r * N_EDGES,
                cnt, bucket, N_EDGES);
            gather_mean_fb_kernel<<<(N_NODES * 64 + 255) / 256, 256, 0, stream>>>(
                x, cnt, bucket, A);
            gemm_mfma_kernel<IN_F, IN_F><<<NPAD / 64, 256, 0, stream>>>(
                A, BT, r * IN_F, out, h_bias, r == 0, r == N_REL - 1);
        }
    }
}

// Round 9
// 453.279 us; speedup vs baseline: 2.0304x; 1.3577x over previous
//
#include <hip/hip_runtime.h>

#define N_NODES  50000
#define NPAD     50048          // 782 * 64
#define IN_F     128
#define OUT_F    128
#define N_REL    8
#define N_BASES  4
#define N_EDGES  800000
#define E4       (N_EDGES / 4)  // 200000
#define KTOT     (N_REL * IN_F) // 1024
#define CAP      64             // fallback per-node bucket cap
#define NBIN     782            // bins of 64 nodes per relation
#define NPART    32             // partition blocks per relation
#define EPART4   (E4 / NPART)   // 6250 int4 per partition block
#define SORTCAP  1536           // Poisson(1024) + 16 sigma

// prep_fused block-range split
#define G_PART   (N_REL * NPART)   // 256
#define G_XB     6250              // N*IN_F/4/256
#define G_WS     512               // 128*1024/256

typedef unsigned short ushort_t;
typedef __attribute__((ext_vector_type(8))) short short8;
typedef __attribute__((ext_vector_type(4))) float f32x4;
typedef __attribute__((ext_vector_type(4))) int  int4v;

__device__ inline ushort_t f2bf(float f) {
    unsigned u = __float_as_uint(f);
    return (ushort_t)((u + 0x7fffu + ((u >> 16) & 1u)) >> 16);   // RNE
}
__device__ inline float bflo(unsigned v) { return __uint_as_float(v << 16); }
__device__ inline float bfhi(unsigned v) { return __uint_as_float(v & 0xffff0000u); }

__device__ inline void ws_body(const float* __restrict__ weight,
                               const float* __restrict__ w_comp,
                               ushort_t* __restrict__ BT, int idx)
{
    int o  = idx >> 10;
    int ri = idx & 1023;
    int r  = ri >> 7;
    int i  = ri & 127;
    float acc = 0.f;
#pragma unroll
    for (int b = 0; b < N_BASES; ++b)
        acc += w_comp[r * N_BASES + b] * weight[b * (IN_F * OUT_F) + i * OUT_F + o];
    BT[idx] = f2bf(acc);
}

// Fused prep: [0,G_PART) per-chunk LDS histograms over bins (no atomics to
// global, contiguous 3KB row writes), [G_PART,+G_XB) x->bf16, [..,+G_WS) BT.
__global__ __launch_bounds__(256) void prep_fused_kernel(
    const float* __restrict__ weight,
    const float* __restrict__ w_comp,
    const float4* __restrict__ x4,
    const int4v* __restrict__ dst4,
    ushort_t* __restrict__ BT,
    uint2* __restrict__ xb,
    int* __restrict__ hists)           // [256][NBIN]
{
    int bid = blockIdx.x;
    if (bid < G_PART) {
        __shared__ int h[NBIN];
        int r = bid >> 5, blk = bid & 31;
        for (int i = threadIdx.x; i < NBIN; i += 256) h[i] = 0;
        __syncthreads();
        const int4v* d4 = dst4 + (size_t)r * E4 + (size_t)blk * EPART4;
        for (int i = threadIdx.x; i < EPART4; i += 256) {
            int4v d = __builtin_nontemporal_load(&d4[i]);
            atomicAdd(&h[d.x >> 6], 1);
            atomicAdd(&h[d.y >> 6], 1);
            atomicAdd(&h[d.z >> 6], 1);
            atomicAdd(&h[d.w >> 6], 1);
        }
        __syncthreads();
        int* hrow = hists + (size_t)bid * NBIN;
        for (int i = threadIdx.x; i < NBIN; i += 256) hrow[i] = h[i];
    } else if (bid < G_PART + G_XB) {
        int i = (bid - G_PART) * 256 + threadIdx.x;   // over N*IN_F/4 exact
        float4 v = x4[i];
        uint2 p;
        p.x = (unsigned)f2bf(v.x) | ((unsigned)f2bf(v.y) << 16);
        p.y = (unsigned)f2bf(v.z) | ((unsigned)f2bf(v.w) << 16);
        xb[i] = p;
    } else {
        ws_body(weight, w_comp, BT, (bid - G_PART - G_XB) * 256 + threadIdx.x);
    }
}

// Standalone ws kernel (fallback path)
__global__ __launch_bounds__(256) void ws_only_kernel(
    const float* __restrict__ weight,
    const float* __restrict__ w_comp,
    ushort_t* __restrict__ BT)
{
    ws_body(weight, w_comp, BT, blockIdx.x * 256 + threadIdx.x);
}

// One block per relation (1024 thr): (a) column-scan the 32 block-histograms
// per bin in-place -> per-block local offsets, totals in LDS; (b) block-scan
// the 782 bin totals -> absolute bin bases in earr (+ sentinel).
__global__ __launch_bounds__(1024) void scan2_kernel(
    int* __restrict__ hists,           // [8][32][NBIN], in-place -> local offs
    int* __restrict__ binbase)         // [8*NBIN + 1]
{
    __shared__ int tot[NBIN];
    __shared__ int wsum[16];
    int r = blockIdx.x, t = threadIdx.x;
    if (t < NBIN) {
        int run = 0;
        int* col = hists + (size_t)r * NPART * NBIN + t;
#pragma unroll
        for (int blk = 0; blk < NPART; ++blk) {
            int v = col[(size_t)blk * NBIN];
            col[(size_t)blk * NBIN] = run;
            run += v;
        }
        tot[t] = run;
    }
    __syncthreads();
    int lane = t & 63, wid = t >> 6;
    int v = (t < NBIN) ? tot[t] : 0;
    int inc = v;
#pragma unroll
    for (int off = 1; off < 64; off <<= 1) {
        int u = __shfl_up(inc, off);
        if (lane >= off) inc += u;
    }
    if (lane == 63) wsum[wid] = inc;
    __syncthreads();
    if (t < 16) {
        int iw = wsum[t];
#pragma unroll
        for (int off = 1; off < 16; off <<= 1) {
            int u = __shfl_up(iw, off, 16);
            if (t >= off) iw += u;
        }
        wsum[t] = iw;
    }
    __syncthreads();
    int base = (wid == 0) ? 0 : wsum[wid - 1];
    if (t < NBIN) binbase[r * NBIN + t] = r * N_EDGES + base + inc - v;
    if (r == N_REL - 1 && t == 0) binbase[N_REL * NBIN] = N_REL * N_EDGES;
}

// Each block streams its chunk into its PRIVATE windows of binbuf (cursor =
// binbase + its local offset). No global atomics; stores are block-exclusive
// short sequential runs -> no cross-XCD line ping-pong.
__global__ __launch_bounds__(256) void place_part_kernel(
    const int4v* __restrict__ src4,
    const int4v* __restrict__ dst4,
    const int* __restrict__ hists,     // local offsets after scan2
    const int* __restrict__ binbase,
    unsigned* __restrict__ binbuf)
{
    __shared__ int cur[NBIN];
    int bid = blockIdx.x;
    int r = bid >> 5, blk = bid & 31;
    const int* hrow = hists + (size_t)bid * NBIN;
    const int* bb   = binbase + r * NBIN;
    for (int i = threadIdx.x; i < NBIN; i += 256)
        cur[i] = bb[i] + hrow[i];
    __syncthreads();
    const int4v* s4 = src4 + (size_t)r * E4 + (size_t)blk * EPART4;
    const int4v* d4 = dst4 + (size_t)r * E4 + (size_t)blk * EPART4;
    for (int i = threadIdx.x; i < EPART4; i += 256) {
        int4v s = __builtin_nontemporal_load(&s4[i]);
        int4v d = __builtin_nontemporal_load(&d4[i]);
#define PUT(DV, SV) { int pos = atomicAdd(&cur[(DV) >> 6], 1);                \
        binbuf[pos] = (unsigned)(SV) | ((unsigned)((DV) & 63) << 16); }
        PUT(d.x, s.x) PUT(d.y, s.y) PUT(d.z, s.z) PUT(d.w, s.w)
#undef PUT
    }
}

// One block per bin: LDS histogram (writes cnt/start for the gather), LDS
// counting-sort, then CONTIGUOUS stream of the sorted window into earr.
__global__ __launch_bounds__(256) void bin_sort_kernel(
    const unsigned* __restrict__ binbuf,
    const int* __restrict__ binbase,
    int* __restrict__ cnt,
    int* __restrict__ start,
    ushort_t* __restrict__ earr)
{
    __shared__ unsigned ent[SORTCAP];  // 6 KB
    __shared__ ushort_t srt[SORTCAP];  // 3 KB
    __shared__ int h[64], scur[64];

    int gb = blockIdx.x;               // r*NBIN + bin
    int r  = gb / NBIN;
    int bin = gb - r * NBIN;
    int t = threadIdx.x;
    int base = binbase[gb];
    int cb = min(binbase[gb + 1] - base, SORTCAP);

    if (t < 64) h[t] = 0;
    __syncthreads();
    for (int i = t; i < cb; i += 256) {
        unsigned e = binbuf[(size_t)base + i];
        ent[i] = e;
        atomicAdd(&h[e >> 16], 1);
    }
    __syncthreads();
    if (t < 64) {                      // wave 0: scan 64 node counts
        int v = h[t];
        int inc = v;
#pragma unroll
        for (int off = 1; off < 64; off <<= 1) {
            int u = __shfl_up(inc, off);
            if (t >= off) inc += u;
        }
        int excl = inc - v;
        scur[t] = excl;
        int gn = bin * 64 + t;
        if (gn < N_NODES) {
            cnt[r * N_NODES + gn]   = v;
            start[r * N_NODES + gn] = base + excl;
        }
    }
    __syncthreads();
    for (int i = t; i < cb; i += 256) {
        unsigned e = ent[i];
        int p = atomicAdd(&scur[e >> 16], 1);
        srt[p] = (ushort_t)(e & 0xFFFFu);
    }
    __syncthreads();
    for (int i = t; i < cb; i += 256)
        earr[(size_t)base + i] = srt[i];
}

// One wave per (relation, node). start[] = absolute begin offset in earr.
// 4-deep gather pipeline over 256B bf16 rows of xb.
__global__ __launch_bounds__(256) void gather_csr_kernel(
    const unsigned* __restrict__ xb,   // [N][64] dwords
    const int* __restrict__ cnt,
    const int* __restrict__ start,
    const ushort_t* __restrict__ earr,
    ushort_t* __restrict__ A)          // [NPAD][KTOT]
{
    int r = blockIdx.x & 7;
    int n = (blockIdx.x >> 3) * 4 + ((int)threadIdx.x >> 6);
    int lane = threadIdx.x & 63;
    int slot = r * N_NODES + n;
    int c = cnt[slot];
    const ushort_t* ep = earr + start[slot];

    float ax = 0.f, ay = 0.f, bx = 0.f, by = 0.f;
    for (int base = 0; base < c; base += 64) {
        int m = min(c - base, 64);
        int sid = (lane < m) ? (int)ep[base + lane] : 0;
        int e = 0;
        for (; e + 4 <= m; e += 4) {
            int s0 = __shfl(sid, e);
            int s1 = __shfl(sid, e + 1);
            int s2 = __shfl(sid, e + 2);
            int s3 = __shfl(sid, e + 3);
            unsigned v0 = xb[(size_t)s0 * 64 + lane];
            unsigned v1 = xb[(size_t)s1 * 64 + lane];
            unsigned v2 = xb[(size_t)s2 * 64 + lane];
            unsigned v3 = xb[(size_t)s3 * 64 + lane];
            ax += bflo(v0); ay += bfhi(v0);
            bx += bflo(v1); by += bfhi(v1);
            ax += bflo(v2); ay += bfhi(v2);
            bx += bflo(v3); by += bfhi(v3);
        }
        for (; e < m; ++e) {
            int s0 = __shfl(sid, e);
            unsigned v0 = xb[(size_t)s0 * 64 + lane];
            ax += bflo(v0); ay += bfhi(v0);
        }
    }
    const float inv = 1.0f / fmaxf((float)c, 1.0f);
    unsigned lo = f2bf((ax + bx) * inv);
    unsigned hi = f2bf((ay + by) * inv);
    ((unsigned*)(A + (size_t)n * KTOT + r * IN_F))[lane] = lo | (hi << 16);
}

// ---------------- fallback-path kernels (small workspace) ----------------
__global__ __launch_bounds__(256) void bucket_fill_kernel(
    const int* __restrict__ src,
    const int* __restrict__ dst,
    int* __restrict__ cnt,
    ushort_t* __restrict__ bucket,
    int nedges)
{
    int e = blockIdx.x * 256 + threadIdx.x;
    if (e >= nedges) return;
    int d = dst[e];
    int pos = atomicAdd(&cnt[d], 1);
    if (pos < CAP)
        bucket[(size_t)d * CAP + pos] = (ushort_t)src[e];
}

__global__ __launch_bounds__(256) void gather_mean_fb_kernel(
    const float* __restrict__ x,
    const int* __restrict__ cnt,
    const ushort_t* __restrict__ bucket,
    ushort_t* __restrict__ A)
{
    int wv = (blockIdx.x * 256 + threadIdx.x) >> 6;
    if (wv >= N_NODES) return;
    int lane = threadIdx.x & 63;
    int c  = cnt[wv];
    int cc = min(c, CAP);
    int sid = (lane < cc) ? (int)bucket[(size_t)wv * CAP + lane] : 0;

    float ax = 0.f, ay = 0.f, bx = 0.f, by = 0.f;
    int e = 0;
    for (; e + 2 <= cc; e += 2) {
        int s0 = __shfl(sid, e);
        int s1 = __shfl(sid, e + 1);
        const float2 v0 = *(const float2*)(x + (size_t)s0 * IN_F + lane * 2);
        const float2 v1 = *(const float2*)(x + (size_t)s1 * IN_F + lane * 2);
        ax += v0.x; ay += v0.y;
        bx += v1.x; by += v1.y;
    }
    if (e < cc) {
        int s0 = __shfl(sid, e);
        const float2 v0 = *(const float2*)(x + (size_t)s0 * IN_F + lane * 2);
        ax += v0.x; ay += v0.y;
    }
    const float inv = 1.0f / fmaxf((float)c, 1.0f);
    unsigned lo = f2bf((ax + bx) * inv);
    unsigned hi = f2bf((ay + by) * inv);
    ((unsigned*)(A + (size_t)wv * IN_F))[lane] = lo | (hi << 16);
}

// C[rows x 128] (+)= A[rows x K]_bf16 @ B (BT stored [128][KTOT]).
// Block 256 = 4 waves; tile 64 rows x 128 cols; wave = 32 rows x 64 cols.
template <int K, int LDA>
__global__ __launch_bounds__(256) void gemm_mfma_kernel(
    const ushort_t* __restrict__ A,
    const ushort_t* __restrict__ BT, int kbase,
    float* __restrict__ out, const float* __restrict__ bias,
    int first, int last)
{
    int tid  = threadIdx.x;
    int wave = tid >> 6, lane = tid & 63;
    int rowf = lane & 15, kg = lane >> 4;
    int rbase = blockIdx.x * 64 + (wave & 1) * 32;
    int cbase = (wave >> 1) * 64;

    f32x4 acc[2][4];
#pragma unroll
    for (int t = 0; t < 2; ++t)
#pragma unroll
        for (int c = 0; c < 4; ++c) acc[t][c] = (f32x4){0.f, 0.f, 0.f, 0.f};

    const short8* Ar0 = (const short8*)(A + (size_t)(rbase + rowf) * LDA + kg * 8);
    const short8* Ar1 = (const short8*)(A + (size_t)(rbase + 16 + rowf) * LDA + kg * 8);
    const ushort_t* Bb = BT + (size_t)(cbase + rowf) * KTOT + kbase + kg * 8;

    short8 a0 = __builtin_nontemporal_load(Ar0);
    short8 a1 = __builtin_nontemporal_load(Ar1);
    short8 b0 = *(const short8*)(Bb);
    short8 b1 = *(const short8*)(Bb + 16 * KTOT);
    short8 b2 = *(const short8*)(Bb + 32 * KTOT);
    short8 b3 = *(const short8*)(Bb + 48 * KTOT);

#pragma unroll
    for (int k0 = 0; k0 < K; k0 += 32) {
        short8 na0 = a0, na1 = a1, nb0 = b0, nb1 = b1, nb2 = b2, nb3 = b3;
        if (k0 + 32 < K) {
            int kk = (k0 + 32) / 8;                   // in short8 units
            na0 = __builtin_nontemporal_load(Ar0 + kk);
            na1 = __builtin_nontemporal_load(Ar1 + kk);
            nb0 = *(const short8*)(Bb + k0 + 32);
            nb1 = *(const short8*)(Bb + 16 * KTOT + k0 + 32);
            nb2 = *(const short8*)(Bb + 32 * KTOT + k0 + 32);
            nb3 = *(const short8*)(Bb + 48 * KTOT + k0 + 32);
        }
        acc[0][0] = __builtin_amdgcn_mfma_f32_16x16x32_bf16(a0, b0, acc[0][0], 0, 0, 0);
        acc[1][0] = __builtin_amdgcn_mfma_f32_16x16x32_bf16(a1, b0, acc[1][0], 0, 0, 0);
        acc[0][1] = __builtin_amdgcn_mfma_f32_16x16x32_bf16(a0, b1, acc[0][1], 0, 0, 0);
        acc[1][1] = __builtin_amdgcn_mfma_f32_16x16x32_bf16(a1, b1, acc[1][1], 0, 0, 0);
        acc[0][2] = __builtin_amdgcn_mfma_f32_16x16x32_bf16(a0, b2, acc[0][2], 0, 0, 0);
        acc[1][2] = __builtin_amdgcn_mfma_f32_16x16x32_bf16(a1, b2, acc[1][2], 0, 0, 0);
        acc[0][3] = __builtin_amdgcn_mfma_f32_16x16x32_bf16(a0, b3, acc[0][3], 0, 0, 0);
        acc[1][3] = __builtin_amdgcn_mfma_f32_16x16x32_bf16(a1, b3, acc[1][3], 0, 0, 0);
        a0 = na0; a1 = na1; b0 = nb0; b1 = nb1; b2 = nb2; b3 = nb3;
    }

    // C/D layout: col = lane&15, row = (lane>>4)*4 + j
#pragma unroll
    for (int t = 0; t < 2; ++t) {
#pragma unroll
        for (int c = 0; c < 4; ++c) {
            int col = cbase + c * 16 + rowf;
#pragma unroll
            for (int j = 0; j < 4; ++j) {
                int row = rbase + t * 16 + kg * 4 + j;
                if (row < N_NODES) {
                    float v = acc[t][c][j];
                    float* p = out + (size_t)row * OUT_F + col;
                    if (!first) v += *p;
                    if (last)  v = fmaxf(v + bias[col], 0.f);
                    *p = v;
                }
            }
        }
    }
}

extern "C" void kernel_launch(void* const* d_in, const int* in_sizes, int n_in,
                              void* d_out, int out_size, void* d_ws, size_t ws_size,
                              hipStream_t stream) {
    const float* x      = (const float*)d_in[0];
    const float* weight = (const float*)d_in[1];
    const float* w_comp = (const float*)d_in[2];
    const float* h_bias = (const float*)d_in[3];
    const int*   src    = (const int*)d_in[4];
    const int*   dst    = (const int*)d_in[5];
    float* out = (float*)d_out;

    char* wsb = (char*)d_ws;
    const size_t btSz    = (size_t)OUT_F * KTOT * 2;               // 256 KB
    const size_t histSz  = (size_t)G_PART * NBIN * 4;              // 800 KB
    const size_t bbaseSz = (size_t)((N_REL * NBIN + 1) * 4 + 255) & ~(size_t)255;
    const size_t cntSz   = (size_t)N_REL * N_NODES * 4;            // 1.6 MB
    const size_t bbufSz  = (size_t)N_REL * N_EDGES * 4;            // 25.6 MB
    const size_t earrSz  = (size_t)N_REL * N_EDGES * 2;            // 12.8 MB
    const size_t aSz     = (size_t)NPAD * KTOT * 2;                // 102.5 MB
    const size_t xbSz    = (size_t)N_NODES * 64 * 4;               // 12.8 MB
    const size_t need    = btSz + histSz + bbaseSz + 2 * cntSz
                         + bbufSz + earrSz + aSz + xbSz;           // ~158 MB

    ushort_t* BT = (ushort_t*)wsb;

    if (ws_size >= need) {
        size_t off = btSz;
        int*      hists   = (int*)(wsb + off);      off += histSz;
        int*      binbase = (int*)(wsb + off);      off += bbaseSz;
        int*      cnt     = (int*)(wsb + off);      off += cntSz;
        int*      start   = (int*)(wsb + off);      off += cntSz;
        unsigned* binbuf  = (unsigned*)(wsb + off); off += bbufSz;
        ushort_t* earr    = (ushort_t*)(wsb + off); off += earrSz;
        ushort_t* A       = (ushort_t*)(wsb + off); off += aSz;
        unsigned* xb      = (unsigned*)(wsb + off);

        prep_fused_kernel<<<G_PART + G_XB + G_WS, 256, 0, stream>>>(
            weight, w_comp, (const float4*)x, (const int4v*)dst,
            BT, (uint2*)xb, hists);
        scan2_kernel<<<N_REL, 1024, 0, stream>>>(hists, binbase);
        place_part_kernel<<<G_PART, 256, 0, stream>>>(
            (const int4v*)src, (const int4v*)dst, hists, binbase, binbuf);
        bin_sort_kernel<<<N_REL * NBIN, 256, 0, stream>>>(
            binbuf, binbase, cnt, start, earr);
        gather_csr_kernel<<<8 * (N_NODES / 4), 256, 0, stream>>>(
            xb, cnt, start, earr, A);
        gemm_mfma_kernel<KTOT, KTOT><<<NPAD / 64, 256, 0, stream>>>(
            A, BT, 0, out, h_bias, 1, 1);
    } else {
        // per-relation fallback (~19.7 MB)
        const size_t cntSz1 = (size_t)N_NODES * 4;
        const size_t bktSz1 = (size_t)N_NODES * CAP * 2;
        int*      cnt    = (int*)(wsb + btSz);
        ushort_t* bucket = (ushort_t*)(wsb + btSz + cntSz1);
        ushort_t* A      = (ushort_t*)(wsb + btSz + cntSz1 + bktSz1);

        ws_only_kernel<<<G_WS, 256, 0, stream>>>(weight, w_comp, BT);
        for (int r = 0; r < N_REL; ++r) {
            hipMemsetAsync(cnt, 0, cntSz1, stream);
            bucket_fill_kernel<<<(N_EDGES + 255) / 256, 256, 0, stream>>>(
                src + (size_t)r * N_EDGES, dst + (size_t)r * N_EDGES,
                cnt, bucket, N_EDGES);
            gather_mean_fb_kernel<<<(N_NODES * 64 + 255) / 256, 256, 0, stream>>>(
                x, cnt, bucket, A);
            gemm_mfma_kernel<IN_F, IN_F><<<NPAD / 64, 256, 0, stream>>>(
                A, BT, r * IN_F, out, h_bias, r == 0, r == N_REL - 1);
        }
    }
}

// Round 11
// 439.747 us; speedup vs baseline: 2.0928x; 1.0308x over previous
//
#include <hip/hip_runtime.h>

#define N_NODES  50000
#define NPAD     50048          // 782 * 64
#define IN_F     128
#define OUT_F    128
#define N_REL    8
#define N_BASES  4
#define N_EDGES  800000
#define E4       (N_EDGES / 4)  // 200000
#define KTOT     (N_REL * IN_F) // 1024
#define CAP      64             // fallback per-node bucket cap
#define NBIN     782            // bins of 64 nodes per relation
#define NPART    32             // partition blocks per relation
#define EPART4   (E4 / NPART)   // 6250 int4 per partition block
#define SORTCAP  1536           // Poisson(1024) + 16 sigma

// prep_fused block-range split
#define G_PART   (N_REL * NPART)   // 256
#define G_XB     6250              // N*IN_F/4/256
#define G_WS     512               // 128*1024/256

typedef unsigned short ushort_t;
typedef __attribute__((ext_vector_type(8))) short short8;
typedef __attribute__((ext_vector_type(4))) float f32x4;
typedef __attribute__((ext_vector_type(4))) int  int4v;

__device__ inline ushort_t f2bf(float f) {
    unsigned u = __float_as_uint(f);
    return (ushort_t)((u + 0x7fffu + ((u >> 16) & 1u)) >> 16);   // RNE
}
__device__ inline float bflo(unsigned v) { return __uint_as_float(v << 16); }
__device__ inline float bfhi(unsigned v) { return __uint_as_float(v & 0xffff0000u); }

__device__ inline void ws_body(const float* __restrict__ weight,
                               const float* __restrict__ w_comp,
                               ushort_t* __restrict__ BT, int idx)
{
    int o  = idx >> 10;
    int ri = idx & 1023;
    int r  = ri >> 7;
    int i  = ri & 127;
    float acc = 0.f;
#pragma unroll
    for (int b = 0; b < N_BASES; ++b)
        acc += w_comp[r * N_BASES + b] * weight[b * (IN_F * OUT_F) + i * OUT_F + o];
    BT[idx] = f2bf(acc);
}

// Fused prep: [0,G_PART) per-chunk LDS histograms over bins (no atomics to
// global, contiguous 3KB row writes), [G_PART,+G_XB) x->bf16, [..,+G_WS) BT.
__global__ __launch_bounds__(256) void prep_fused_kernel(
    const float* __restrict__ weight,
    const float* __restrict__ w_comp,
    const float4* __restrict__ x4,
    const int4v* __restrict__ dst4,
    ushort_t* __restrict__ BT,
    uint2* __restrict__ xb,
    int* __restrict__ hists)           // [256][NBIN]
{
    int bid = blockIdx.x;
    if (bid < G_PART) {
        __shared__ int h[NBIN];
        int r = bid >> 5, blk = bid & 31;
        for (int i = threadIdx.x; i < NBIN; i += 256) h[i] = 0;
        __syncthreads();
        const int4v* d4 = dst4 + (size_t)r * E4 + (size_t)blk * EPART4;
        for (int i = threadIdx.x; i < EPART4; i += 256) {
            int4v d = __builtin_nontemporal_load(&d4[i]);
            atomicAdd(&h[d.x >> 6], 1);
            atomicAdd(&h[d.y >> 6], 1);
            atomicAdd(&h[d.z >> 6], 1);
            atomicAdd(&h[d.w >> 6], 1);
        }
        __syncthreads();
        int* hrow = hists + (size_t)bid * NBIN;
        for (int i = threadIdx.x; i < NBIN; i += 256) hrow[i] = h[i];
    } else if (bid < G_PART + G_XB) {
        int i = (bid - G_PART) * 256 + threadIdx.x;   // over N*IN_F/4 exact
        float4 v = x4[i];
        uint2 p;
        p.x = (unsigned)f2bf(v.x) | ((unsigned)f2bf(v.y) << 16);
        p.y = (unsigned)f2bf(v.z) | ((unsigned)f2bf(v.w) << 16);
        xb[i] = p;
    } else {
        ws_body(weight, w_comp, BT, (bid - G_PART - G_XB) * 256 + threadIdx.x);
    }
}

// Standalone ws kernel (fallback path)
__global__ __launch_bounds__(256) void ws_only_kernel(
    const float* __restrict__ weight,
    const float* __restrict__ w_comp,
    ushort_t* __restrict__ BT)
{
    ws_body(weight, w_comp, BT, blockIdx.x * 256 + threadIdx.x);
}

// One block per relation (1024 thr): (a) column-scan the 32 block-histograms
// per bin in-place -> per-block local offsets, totals in LDS; (b) block-scan
// the 782 bin totals -> absolute bin bases in earr (+ sentinel).
__global__ __launch_bounds__(1024) void scan2_kernel(
    int* __restrict__ hists,           // [8][32][NBIN], in-place -> local offs
    int* __restrict__ binbase)         // [8*NBIN + 1]
{
    __shared__ int tot[NBIN];
    __shared__ int wsum[16];
    int r = blockIdx.x, t = threadIdx.x;
    if (t < NBIN) {
        int run = 0;
        int* col = hists + (size_t)r * NPART * NBIN + t;
#pragma unroll
        for (int blk = 0; blk < NPART; ++blk) {
            int v = col[(size_t)blk * NBIN];
            col[(size_t)blk * NBIN] = run;
            run += v;
        }
        tot[t] = run;
    }
    __syncthreads();
    int lane = t & 63, wid = t >> 6;
    int v = (t < NBIN) ? tot[t] : 0;
    int inc = v;
#pragma unroll
    for (int off = 1; off < 64; off <<= 1) {
        int u = __shfl_up(inc, off);
        if (lane >= off) inc += u;
    }
    if (lane == 63) wsum[wid] = inc;
    __syncthreads();
    if (t < 16) {
        int iw = wsum[t];
#pragma unroll
        for (int off = 1; off < 16; off <<= 1) {
            int u = __shfl_up(iw, off, 16);
            if (t >= off) iw += u;
        }
        wsum[t] = iw;
    }
    __syncthreads();
    int base = (wid == 0) ? 0 : wsum[wid - 1];
    if (t < NBIN) binbase[r * NBIN + t] = r * N_EDGES + base + inc - v;
    if (r == N_REL - 1 && t == 0) binbase[N_REL * NBIN] = N_REL * N_EDGES;
}

// Each block streams its chunk into its PRIVATE windows of binbuf (cursor =
// binbase + its local offset). No global atomics; stores are block-exclusive
// short sequential runs -> no cross-XCD line ping-pong.
__global__ __launch_bounds__(256) void place_part_kernel(
    const int4v* __restrict__ src4,
    const int4v* __restrict__ dst4,
    const int* __restrict__ hists,     // local offsets after scan2
    const int* __restrict__ binbase,
    unsigned* __restrict__ binbuf)
{
    __shared__ int cur[NBIN];
    int bid = blockIdx.x;
    int r = bid >> 5, blk = bid & 31;
    const int* hrow = hists + (size_t)bid * NBIN;
    const int* bb   = binbase + r * NBIN;
    for (int i = threadIdx.x; i < NBIN; i += 256)
        cur[i] = bb[i] + hrow[i];
    __syncthreads();
    const int4v* s4 = src4 + (size_t)r * E4 + (size_t)blk * EPART4;
    const int4v* d4 = dst4 + (size_t)r * E4 + (size_t)blk * EPART4;
    for (int i = threadIdx.x; i < EPART4; i += 256) {
        int4v s = __builtin_nontemporal_load(&s4[i]);
        int4v d = __builtin_nontemporal_load(&d4[i]);
#define PUT(DV, SV) { int pos = atomicAdd(&cur[(DV) >> 6], 1);                \
        binbuf[pos] = (unsigned)(SV) | ((unsigned)((DV) & 63) << 16); }
        PUT(d.x, s.x) PUT(d.y, s.y) PUT(d.z, s.z) PUT(d.w, s.w)
#undef PUT
    }
}

// One block per bin: LDS histogram (writes cnt/start for the gather), LDS
// counting-sort, then CONTIGUOUS stream of the sorted window into earr.
__global__ __launch_bounds__(256) void bin_sort_kernel(
    const unsigned* __restrict__ binbuf,
    const int* __restrict__ binbase,
    int* __restrict__ cnt,
    int* __restrict__ start,
    ushort_t* __restrict__ earr)
{
    __shared__ unsigned ent[SORTCAP];  // 6 KB
    __shared__ ushort_t srt[SORTCAP];  // 3 KB
    __shared__ int h[64], scur[64];

    int gb = blockIdx.x;               // r*NBIN + bin
    int r  = gb / NBIN;
    int bin = gb - r * NBIN;
    int t = threadIdx.x;
    int base = binbase[gb];
    int cb = min(binbase[gb + 1] - base, SORTCAP);

    if (t < 64) h[t] = 0;
    __syncthreads();
    for (int i = t; i < cb; i += 256) {
        unsigned e = binbuf[(size_t)base + i];
        ent[i] = e;
        atomicAdd(&h[e >> 16], 1);
    }
    __syncthreads();
    if (t < 64) {                      // wave 0: scan 64 node counts
        int v = h[t];
        int inc = v;
#pragma unroll
        for (int off = 1; off < 64; off <<= 1) {
            int u = __shfl_up(inc, off);
            if (t >= off) inc += u;
        }
        int excl = inc - v;
        scur[t] = excl;
        int gn = bin * 64 + t;
        if (gn < N_NODES) {
            cnt[r * N_NODES + gn]   = v;
            start[r * N_NODES + gn] = base + excl;
        }
    }
    __syncthreads();
    for (int i = t; i < cb; i += 256) {
        unsigned e = ent[i];
        int p = atomicAdd(&scur[e >> 16], 1);
        srt[p] = (ushort_t)(e & 0xFFFFu);
    }
    __syncthreads();
    for (int i = t; i < cb; i += 256)
        earr[(size_t)base + i] = srt[i];
}

// One wave per (relation, node). Half-wave edge-pairing: lanes 0-31 process
// even edges, lanes 32-63 odd edges; each lane loads uint2 (8B, 4 features).
// NOTE: every __shfl here executes with ALL 64 lanes active (cross-lane ops
// must never sit inside a lane-divergent branch — R10 bug). Tail uses a
// wave-uniform branch with only the load/accumulate predicated on h.
__global__ __launch_bounds__(256) void gather_csr_kernel(
    const uint2* __restrict__ xb2,     // [N][32] uint2 (bf16-pair rows)
    const int* __restrict__ cnt,
    const int* __restrict__ start,
    const ushort_t* __restrict__ earr,
    ushort_t* __restrict__ A)          // [NPAD][KTOT]
{
    int r = blockIdx.x & 7;
    int n = (blockIdx.x >> 3) * 4 + ((int)threadIdx.x >> 6);
    int lane = threadIdx.x & 63;
    int h  = lane >> 5;                // half: 0 = even edge, 1 = odd edge
    int fl = lane & 31;                // feature uint2 index
    int slot = r * N_NODES + n;
    int c = cnt[slot];
    const ushort_t* ep = earr + start[slot];

    float a0 = 0.f, a1 = 0.f, a2 = 0.f, a3 = 0.f;
    for (int base = 0; base < c; base += 64) {
        int m = min(c - base, 64);     // wave-uniform
        int sid = (lane < m) ? (int)ep[base + lane] : 0;
        int e = 0;
        for (; e + 8 <= m; e += 8) {
            int i0 = __shfl(sid, e + 0 + h);
            int i1 = __shfl(sid, e + 2 + h);
            int i2 = __shfl(sid, e + 4 + h);
            int i3 = __shfl(sid, e + 6 + h);
            uint2 v0 = xb2[(size_t)i0 * 32 + fl];
            uint2 v1 = xb2[(size_t)i1 * 32 + fl];
            uint2 v2 = xb2[(size_t)i2 * 32 + fl];
            uint2 v3 = xb2[(size_t)i3 * 32 + fl];
            a0 += bflo(v0.x); a1 += bfhi(v0.x); a2 += bflo(v0.y); a3 += bfhi(v0.y);
            a0 += bflo(v1.x); a1 += bfhi(v1.x); a2 += bflo(v1.y); a3 += bfhi(v1.y);
            a0 += bflo(v2.x); a1 += bfhi(v2.x); a2 += bflo(v2.y); a3 += bfhi(v2.y);
            a0 += bflo(v3.x); a1 += bfhi(v3.x); a2 += bflo(v3.y); a3 += bfhi(v3.y);
        }
        for (; e + 2 <= m; e += 2) {   // uniform bounds, all lanes in shfl
            int i0 = __shfl(sid, e + h);
            uint2 v0 = xb2[(size_t)i0 * 32 + fl];
            a0 += bflo(v0.x); a1 += bfhi(v0.x); a2 += bflo(v0.y); a3 += bfhi(v0.y);
        }
        if (e < m) {                   // uniform branch: shfl fully converged
            int i0 = __shfl(sid, e);
            if (h == 0) {              // only the load/accumulate is predicated
                uint2 v0 = xb2[(size_t)i0 * 32 + fl];
                a0 += bflo(v0.x); a1 += bfhi(v0.x);
                a2 += bflo(v0.y); a3 += bfhi(v0.y);
            }
        }
    }
    // combine the two halves (features identical across halves)
    a0 += __shfl_xor(a0, 32);
    a1 += __shfl_xor(a1, 32);
    a2 += __shfl_xor(a2, 32);
    a3 += __shfl_xor(a3, 32);

    if (h == 0) {
        const float inv = 1.0f / fmaxf((float)c, 1.0f);
        uint2 o;
        o.x = (unsigned)f2bf(a0 * inv) | ((unsigned)f2bf(a1 * inv) << 16);
        o.y = (unsigned)f2bf(a2 * inv) | ((unsigned)f2bf(a3 * inv) << 16);
        ((uint2*)(A + (size_t)n * KTOT + r * IN_F))[fl] = o;
    }
}

// ---------------- fallback-path kernels (small workspace) ----------------
__global__ __launch_bounds__(256) void bucket_fill_kernel(
    const int* __restrict__ src,
    const int* __restrict__ dst,
    int* __restrict__ cnt,
    ushort_t* __restrict__ bucket,
    int nedges)
{
    int e = blockIdx.x * 256 + threadIdx.x;
    if (e >= nedges) return;
    int d = dst[e];
    int pos = atomicAdd(&cnt[d], 1);
    if (pos < CAP)
        bucket[(size_t)d * CAP + pos] = (ushort_t)src[e];
}

__global__ __launch_bounds__(256) void gather_mean_fb_kernel(
    const float* __restrict__ x,
    const int* __restrict__ cnt,
    const ushort_t* __restrict__ bucket,
    ushort_t* __restrict__ A)
{
    int wv = (blockIdx.x * 256 + threadIdx.x) >> 6;
    if (wv >= N_NODES) return;
    int lane = threadIdx.x & 63;
    int c  = cnt[wv];
    int cc = min(c, CAP);
    int sid = (lane < cc) ? (int)bucket[(size_t)wv * CAP + lane] : 0;

    float ax = 0.f, ay = 0.f, bx = 0.f, by = 0.f;
    int e = 0;
    for (; e + 2 <= cc; e += 2) {
        int s0 = __shfl(sid, e);
        int s1 = __shfl(sid, e + 1);
        const float2 v0 = *(const float2*)(x + (size_t)s0 * IN_F + lane * 2);
        const float2 v1 = *(const float2*)(x + (size_t)s1 * IN_F + lane * 2);
        ax += v0.x; ay += v0.y;
        bx += v1.x; by += v1.y;
    }
    if (e < cc) {
        int s0 = __shfl(sid, e);
        const float2 v0 = *(const float2*)(x + (size_t)s0 * IN_F + lane * 2);
        ax += v0.x; ay += v0.y;
    }
    const float inv = 1.0f / fmaxf((float)c, 1.0f);
    unsigned lo = f2bf((ax + bx) * inv);
    unsigned hi = f2bf((ay + by) * inv);
    ((unsigned*)(A + (size_t)wv * IN_F))[lane] = lo | (hi << 16);
}

// C[rows x 128] (+)= A[rows x K]_bf16 @ B (BT stored [128][KTOT]).
// Block 256 = 4 waves; tile 64 rows x 128 cols; wave = 32 rows x 64 cols.
template <int K, int LDA>
__global__ __launch_bounds__(256) void gemm_mfma_kernel(
    const ushort_t* __restrict__ A,
    const ushort_t* __restrict__ BT, int kbase,
    float* __restrict__ out, const float* __restrict__ bias,
    int first, int last)
{
    int tid  = threadIdx.x;
    int wave = tid >> 6, lane = tid & 63;
    int rowf = lane & 15, kg = lane >> 4;
    int rbase = blockIdx.x * 64 + (wave & 1) * 32;
    int cbase = (wave >> 1) * 64;

    f32x4 acc[2][4];
#pragma unroll
    for (int t = 0; t < 2; ++t)
#pragma unroll
        for (int c = 0; c < 4; ++c) acc[t][c] = (f32x4){0.f, 0.f, 0.f, 0.f};

    const short8* Ar0 = (const short8*)(A + (size_t)(rbase + rowf) * LDA + kg * 8);
    const short8* Ar1 = (const short8*)(A + (size_t)(rbase + 16 + rowf) * LDA + kg * 8);
    const ushort_t* Bb = BT + (size_t)(cbase + rowf) * KTOT + kbase + kg * 8;

    short8 a0 = __builtin_nontemporal_load(Ar0);
    short8 a1 = __builtin_nontemporal_load(Ar1);
    short8 b0 = *(const short8*)(Bb);
    short8 b1 = *(const short8*)(Bb + 16 * KTOT);
    short8 b2 = *(const short8*)(Bb + 32 * KTOT);
    short8 b3 = *(const short8*)(Bb + 48 * KTOT);

#pragma unroll
    for (int k0 = 0; k0 < K; k0 += 32) {
        short8 na0 = a0, na1 = a1, nb0 = b0, nb1 = b1, nb2 = b2, nb3 = b3;
        if (k0 + 32 < K) {
            int kk = (k0 + 32) / 8;                   // in short8 units
            na0 = __builtin_nontemporal_load(Ar0 + kk);
            na1 = __builtin_nontemporal_load(Ar1 + kk);
            nb0 = *(const short8*)(Bb + k0 + 32);
            nb1 = *(const short8*)(Bb + 16 * KTOT + k0 + 32);
            nb2 = *(const short8*)(Bb + 32 * KTOT + k0 + 32);
            nb3 = *(const short8*)(Bb + 48 * KTOT + k0 + 32);
        }
        acc[0][0] = __builtin_amdgcn_mfma_f32_16x16x32_bf16(a0, b0, acc[0][0], 0, 0, 0);
        acc[1][0] = __builtin_amdgcn_mfma_f32_16x16x32_bf16(a1, b0, acc[1][0], 0, 0, 0);
        acc[0][1] = __builtin_amdgcn_mfma_f32_16x16x32_bf16(a0, b1, acc[0][1], 0, 0, 0);
        acc[1][1] = __builtin_amdgcn_mfma_f32_16x16x32_bf16(a1, b1, acc[1][1], 0, 0, 0);
        acc[0][2] = __builtin_amdgcn_mfma_f32_16x16x32_bf16(a0, b2, acc[0][2], 0, 0, 0);
        acc[1][2] = __builtin_amdgcn_mfma_f32_16x16x32_bf16(a1, b2, acc[1][2], 0, 0, 0);
        acc[0][3] = __builtin_amdgcn_mfma_f32_16x16x32_bf16(a0, b3, acc[0][3], 0, 0, 0);
        acc[1][3] = __builtin_amdgcn_mfma_f32_16x16x32_bf16(a1, b3, acc[1][3], 0, 0, 0);
        a0 = na0; a1 = na1; b0 = nb0; b1 = nb1; b2 = nb2; b3 = nb3;
    }

    // C/D layout: col = lane&15, row = (lane>>4)*4 + j
#pragma unroll
    for (int t = 0; t < 2; ++t) {
#pragma unroll
        for (int c = 0; c < 4; ++c) {
            int col = cbase + c * 16 + rowf;
#pragma unroll
            for (int j = 0; j < 4; ++j) {
                int row = rbase + t * 16 + kg * 4 + j;
                if (row < N_NODES) {
                    float v = acc[t][c][j];
                    float* p = out + (size_t)row * OUT_F + col;
                    if (!first) v += *p;
                    if (last)  v = fmaxf(v + bias[col], 0.f);
                    *p = v;
                }
            }
        }
    }
}

extern "C" void kernel_launch(void* const* d_in, const int* in_sizes, int n_in,
                              void* d_out, int out_size, void* d_ws, size_t ws_size,
                              hipStream_t stream) {
    const float* x      = (const float*)d_in[0];
    const float* weight = (const float*)d_in[1];
    const float* w_comp = (const float*)d_in[2];
    const float* h_bias = (const float*)d_in[3];
    const int*   src    = (const int*)d_in[4];
    const int*   dst    = (const int*)d_in[5];
    float* out = (float*)d_out;

    char* wsb = (char*)d_ws;
    const size_t btSz    = (size_t)OUT_F * KTOT * 2;               // 256 KB
    const size_t histSz  = (size_t)G_PART * NBIN * 4;              // 800 KB
    const size_t bbaseSz = (size_t)((N_REL * NBIN + 1) * 4 + 255) & ~(size_t)255;
    const size_t cntSz   = (size_t)N_REL * N_NODES * 4;            // 1.6 MB
    const size_t bbufSz  = (size_t)N_REL * N_EDGES * 4;            // 25.6 MB
    const size_t earrSz  = (size_t)N_REL * N_EDGES * 2;            // 12.8 MB
    const size_t aSz     = (size_t)NPAD * KTOT * 2;                // 102.5 MB
    const size_t xbSz    = (size_t)N_NODES * 64 * 4;               // 12.8 MB
    const size_t need    = btSz + histSz + bbaseSz + 2 * cntSz
                         + bbufSz + earrSz + aSz + xbSz;           // ~158 MB

    ushort_t* BT = (ushort_t*)wsb;

    if (ws_size >= need) {
        size_t off = btSz;
        int*      hists   = (int*)(wsb + off);      off += histSz;
        int*      binbase = (int*)(wsb + off);      off += bbaseSz;
        int*      cnt     = (int*)(wsb + off);      off += cntSz;
        int*      start   = (int*)(wsb + off);      off += cntSz;
        unsigned* binbuf  = (unsigned*)(wsb + off); off += bbufSz;
        ushort_t* earr    = (ushort_t*)(wsb + off); off += earrSz;
        ushort_t* A       = (ushort_t*)(wsb + off); off += aSz;
        unsigned* xb      = (unsigned*)(wsb + off);

        prep_fused_kernel<<<G_PART + G_XB + G_WS, 256, 0, stream>>>(
            weight, w_comp, (const float4*)x, (const int4v*)dst,
            BT, (uint2*)xb, hists);
        scan2_kernel<<<N_REL, 1024, 0, stream>>>(hists, binbase);
        place_part_kernel<<<G_PART, 256, 0, stream>>>(
            (const int4v*)src, (const int4v*)dst, hists, binbase, binbuf);
        bin_sort_kernel<<<N_REL * NBIN, 256, 0, stream>>>(
            binbuf, binbase, cnt, start, earr);
        gather_csr_kernel<<<8 * (N_NODES / 4), 256, 0, stream>>>(
            (const uint2*)xb, cnt, start, earr, A);
        gemm_mfma_kernel<KTOT, KTOT><<<NPAD / 64, 256, 0, stream>>>(
            A, BT, 0, out, h_bias, 1, 1);
    } else {
        // per-relation fallback (~19.7 MB)
        const size_t cntSz1 = (size_t)N_NODES * 4;
        const size_t bktSz1 = (size_t)N_NODES * CAP * 2;
        int*      cnt    = (int*)(wsb + btSz);
        ushort_t* bucket = (ushort_t*)(wsb + btSz + cntSz1);
        ushort_t* A      = (ushort_t*)(wsb + btSz + cntSz1 + bktSz1);

        ws_only_kernel<<<G_WS, 256, 0, stream>>>(weight, w_comp, BT);
        for (int r = 0; r < N_REL; ++r) {
            hipMemsetAsync(cnt, 0, cntSz1, stream);
            bucket_fill_kernel<<<(N_EDGES + 255) / 256, 256, 0, stream>>>(
                src + (size_t)r * N_EDGES, dst + (size_t)r * N_EDGES,
                cnt, bucket, N_EDGES);
            gather_mean_fb_kernel<<<(N_NODES * 64 + 255) / 256, 256, 0, stream>>>(
                x, cnt, bucket, A);
            gemm_mfma_kernel<IN_F, IN_F><<<NPAD / 64, 256, 0, stream>>>(
                A, BT, r * IN_F, out, h_bias, r == 0, r == N_REL - 1);
        }
    }
}

// Round 12
// 415.091 us; speedup vs baseline: 2.2172x; 1.0594x over previous
//
#include <hip/hip_runtime.h>

#define N_NODES  50000
#define NPAD     50048          // 782 * 64
#define IN_F     128
#define OUT_F    128
#define N_REL    8
#define N_BASES  4
#define N_EDGES  800000
#define E4       (N_EDGES / 4)  // 200000
#define KTOT     (N_REL * IN_F) // 1024
#define CAP      64             // fallback per-node bucket cap
#define NBIN     782            // bins of 64 nodes per relation
#define NPART    32             // partition blocks per relation
#define EPART4   (E4 / NPART)   // 6250 int4 per partition block
#define SORTCAP  1536           // Poisson(1024) + 16 sigma

// prep_fused block-range split
#define G_PART   (N_REL * NPART)   // 256
#define G_XB     6250              // N*IN_F/4/256
#define G_WS     512               // 128*1024/256

typedef unsigned short ushort_t;
typedef __attribute__((ext_vector_type(8))) short short8;
typedef __attribute__((ext_vector_type(4))) float f32x4;
typedef __attribute__((ext_vector_type(4))) int  int4v;
typedef __attribute__((ext_vector_type(2))) unsigned uint2v;

__device__ inline ushort_t f2bf(float f) {
    unsigned u = __float_as_uint(f);
    return (ushort_t)((u + 0x7fffu + ((u >> 16) & 1u)) >> 16);   // RNE
}
__device__ inline float bflo(unsigned v) { return __uint_as_float(v << 16); }
__device__ inline float bfhi(unsigned v) { return __uint_as_float(v & 0xffff0000u); }

__device__ inline void ws_body(const float* __restrict__ weight,
                               const float* __restrict__ w_comp,
                               ushort_t* __restrict__ BT, int idx)
{
    int o  = idx >> 10;
    int ri = idx & 1023;
    int r  = ri >> 7;
    int i  = ri & 127;
    float acc = 0.f;
#pragma unroll
    for (int b = 0; b < N_BASES; ++b)
        acc += w_comp[r * N_BASES + b] * weight[b * (IN_F * OUT_F) + i * OUT_F + o];
    BT[idx] = f2bf(acc);
}

// Fused prep: [0,G_PART) per-chunk LDS histograms over bins (no atomics to
// global, contiguous 3KB row writes), [G_PART,+G_XB) x->bf16, [..,+G_WS) BT.
__global__ __launch_bounds__(256) void prep_fused_kernel(
    const float* __restrict__ weight,
    const float* __restrict__ w_comp,
    const float4* __restrict__ x4,
    const int4v* __restrict__ dst4,
    ushort_t* __restrict__ BT,
    uint2* __restrict__ xb,
    int* __restrict__ hists)           // [256][NBIN]
{
    int bid = blockIdx.x;
    if (bid < G_PART) {
        __shared__ int h[NBIN];
        int r = bid >> 5, blk = bid & 31;
        for (int i = threadIdx.x; i < NBIN; i += 256) h[i] = 0;
        __syncthreads();
        const int4v* d4 = dst4 + (size_t)r * E4 + (size_t)blk * EPART4;
        for (int i = threadIdx.x; i < EPART4; i += 256) {
            int4v d = __builtin_nontemporal_load(&d4[i]);
            atomicAdd(&h[d.x >> 6], 1);
            atomicAdd(&h[d.y >> 6], 1);
            atomicAdd(&h[d.z >> 6], 1);
            atomicAdd(&h[d.w >> 6], 1);
        }
        __syncthreads();
        int* hrow = hists + (size_t)bid * NBIN;
        for (int i = threadIdx.x; i < NBIN; i += 256) hrow[i] = h[i];
    } else if (bid < G_PART + G_XB) {
        int i = (bid - G_PART) * 256 + threadIdx.x;   // over N*IN_F/4 exact
        float4 v = x4[i];
        uint2 p;
        p.x = (unsigned)f2bf(v.x) | ((unsigned)f2bf(v.y) << 16);
        p.y = (unsigned)f2bf(v.z) | ((unsigned)f2bf(v.w) << 16);
        xb[i] = p;
    } else {
        ws_body(weight, w_comp, BT, (bid - G_PART - G_XB) * 256 + threadIdx.x);
    }
}

// Standalone ws kernel (fallback path)
__global__ __launch_bounds__(256) void ws_only_kernel(
    const float* __restrict__ weight,
    const float* __restrict__ w_comp,
    ushort_t* __restrict__ BT)
{
    ws_body(weight, w_comp, BT, blockIdx.x * 256 + threadIdx.x);
}

// One block per relation (1024 thr): (a) column-scan the 32 block-histograms
// per bin in-place -> per-block local offsets, totals in LDS; (b) block-scan
// the 782 bin totals -> absolute bin bases in binbuf (+ sentinel).
__global__ __launch_bounds__(1024) void scan2_kernel(
    int* __restrict__ hists,           // [8][32][NBIN], in-place -> local offs
    int* __restrict__ binbase)         // [8*NBIN + 1]
{
    __shared__ int tot[NBIN];
    __shared__ int wsum[16];
    int r = blockIdx.x, t = threadIdx.x;
    if (t < NBIN) {
        int run = 0;
        int* col = hists + (size_t)r * NPART * NBIN + t;
#pragma unroll
        for (int blk = 0; blk < NPART; ++blk) {
            int v = col[(size_t)blk * NBIN];
            col[(size_t)blk * NBIN] = run;
            run += v;
        }
        tot[t] = run;
    }
    __syncthreads();
    int lane = t & 63, wid = t >> 6;
    int v = (t < NBIN) ? tot[t] : 0;
    int inc = v;
#pragma unroll
    for (int off = 1; off < 64; off <<= 1) {
        int u = __shfl_up(inc, off);
        if (lane >= off) inc += u;
    }
    if (lane == 63) wsum[wid] = inc;
    __syncthreads();
    if (t < 16) {
        int iw = wsum[t];
#pragma unroll
        for (int off = 1; off < 16; off <<= 1) {
            int u = __shfl_up(iw, off, 16);
            if (t >= off) iw += u;
        }
        wsum[t] = iw;
    }
    __syncthreads();
    int base = (wid == 0) ? 0 : wsum[wid - 1];
    if (t < NBIN) binbase[r * NBIN + t] = r * N_EDGES + base + inc - v;
    if (r == N_REL - 1 && t == 0) binbase[N_REL * NBIN] = N_REL * N_EDGES;
}

// Each block streams its chunk into its PRIVATE windows of binbuf (cursor =
// binbase + its local offset). No global atomics; stores are block-exclusive
// short sequential runs -> no cross-XCD line ping-pong.
__global__ __launch_bounds__(256) void place_part_kernel(
    const int4v* __restrict__ src4,
    const int4v* __restrict__ dst4,
    const int* __restrict__ hists,     // local offsets after scan2
    const int* __restrict__ binbase,
    unsigned* __restrict__ binbuf)
{
    __shared__ int cur[NBIN];
    int bid = blockIdx.x;
    int r = bid >> 5, blk = bid & 31;
    const int* hrow = hists + (size_t)bid * NBIN;
    const int* bb   = binbase + r * NBIN;
    for (int i = threadIdx.x; i < NBIN; i += 256)
        cur[i] = bb[i] + hrow[i];
    __syncthreads();
    const int4v* s4 = src4 + (size_t)r * E4 + (size_t)blk * EPART4;
    const int4v* d4 = dst4 + (size_t)r * E4 + (size_t)blk * EPART4;
    for (int i = threadIdx.x; i < EPART4; i += 256) {
        int4v s = __builtin_nontemporal_load(&s4[i]);
        int4v d = __builtin_nontemporal_load(&d4[i]);
#define PUT(DV, SV) { int pos = atomicAdd(&cur[(DV) >> 6], 1);                \
        binbuf[pos] = (unsigned)(SV) | ((unsigned)((DV) & 63) << 16); }
        PUT(d.x, s.x) PUT(d.y, s.y) PUT(d.z, s.z) PUT(d.w, s.w)
#undef PUT
    }
}

// Fused sort+gather: one block per (r,bin). (1) load the bin's window to LDS,
// LDS-histogram + counting-sort by local node (bin_sort logic, but results
// stay in LDS). (2) each of the 4 waves gathers 16 nodes, reading edge lists
// from LDS srt[]. Half-wave edge-pairing, uint2 (8B) feature loads, all
// cross-lane ops fully converged (R10 lesson). A written nontemporally so the
// 102.5 MB stream doesn't evict xb from L2.
__global__ __launch_bounds__(256) void sort_gather_kernel(
    const unsigned* __restrict__ binbuf,
    const int* __restrict__ binbase,
    const uint2* __restrict__ xb2,     // [N][32] uint2 (bf16-pair rows)
    ushort_t* __restrict__ A)          // [NPAD][KTOT]
{
    __shared__ unsigned ent[SORTCAP];  // 6 KB
    __shared__ ushort_t srt[SORTCAP];  // 3 KB
    __shared__ int h[64], scur[64], sbeg[64];

    int gb  = blockIdx.x;              // r*NBIN + bin
    int r   = gb / NBIN;
    int bin = gb - r * NBIN;
    int t = threadIdx.x;
    int base = binbase[gb];
    int cb = min(binbase[gb + 1] - base, SORTCAP);

    if (t < 64) h[t] = 0;
    __syncthreads();
    for (int i = t; i < cb; i += 256) {
        unsigned e = __builtin_nontemporal_load(&binbuf[(size_t)base + i]);
        ent[i] = e;
        atomicAdd(&h[e >> 16], 1);
    }
    __syncthreads();
    if (t < 64) {                      // wave 0: scan 64 node counts
        int v = h[t];
        int inc = v;
#pragma unroll
        for (int off = 1; off < 64; off <<= 1) {
            int u = __shfl_up(inc, off);
            if (t >= off) inc += u;
        }
        scur[t] = inc - v;
        sbeg[t] = inc - v;
    }
    __syncthreads();
    for (int i = t; i < cb; i += 256) {
        unsigned e = ent[i];
        int p = atomicAdd(&scur[e >> 16], 1);
        srt[p] = (ushort_t)(e & 0xFFFFu);
    }
    __syncthreads();

    // ---- gather phase ----
    int wv = t >> 6, lane = t & 63;
    int hf = lane >> 5;                // half: 0 = even edge, 1 = odd edge
    int fl = lane & 31;                // feature uint2 index
    int node0 = bin * 64;

    for (int k = 0; k < 16; ++k) {
        int nl  = wv * 16 + k;
        int c   = h[nl];
        int off = sbeg[nl];
        float a0 = 0.f, a1 = 0.f, a2 = 0.f, a3 = 0.f;
        for (int bse = 0; bse < c; bse += 64) {
            int m = min(c - bse, 64);  // wave-uniform
            int sid = (lane < m) ? (int)srt[off + bse + lane] : 0;
            int e = 0;
            for (; e + 8 <= m; e += 8) {
                int i0 = __shfl(sid, e + 0 + hf);
                int i1 = __shfl(sid, e + 2 + hf);
                int i2 = __shfl(sid, e + 4 + hf);
                int i3 = __shfl(sid, e + 6 + hf);
                uint2 v0 = xb2[(size_t)i0 * 32 + fl];
                uint2 v1 = xb2[(size_t)i1 * 32 + fl];
                uint2 v2 = xb2[(size_t)i2 * 32 + fl];
                uint2 v3 = xb2[(size_t)i3 * 32 + fl];
                a0 += bflo(v0.x); a1 += bfhi(v0.x); a2 += bflo(v0.y); a3 += bfhi(v0.y);
                a0 += bflo(v1.x); a1 += bfhi(v1.x); a2 += bflo(v1.y); a3 += bfhi(v1.y);
                a0 += bflo(v2.x); a1 += bfhi(v2.x); a2 += bflo(v2.y); a3 += bfhi(v2.y);
                a0 += bflo(v3.x); a1 += bfhi(v3.x); a2 += bflo(v3.y); a3 += bfhi(v3.y);
            }
            for (; e + 2 <= m; e += 2) {
                int i0 = __shfl(sid, e + hf);
                uint2 v0 = xb2[(size_t)i0 * 32 + fl];
                a0 += bflo(v0.x); a1 += bfhi(v0.x); a2 += bflo(v0.y); a3 += bfhi(v0.y);
            }
            if (e < m) {               // uniform branch; shfl fully converged
                int i0 = __shfl(sid, e);
                if (hf == 0) {
                    uint2 v0 = xb2[(size_t)i0 * 32 + fl];
                    a0 += bflo(v0.x); a1 += bfhi(v0.x);
                    a2 += bflo(v0.y); a3 += bfhi(v0.y);
                }
            }
        }
        a0 += __shfl_xor(a0, 32);
        a1 += __shfl_xor(a1, 32);
        a2 += __shfl_xor(a2, 32);
        a3 += __shfl_xor(a3, 32);

        if (hf == 0) {
            const float inv = 1.0f / fmaxf((float)c, 1.0f);
            uint2v o;
            o.x = (unsigned)f2bf(a0 * inv) | ((unsigned)f2bf(a1 * inv) << 16);
            o.y = (unsigned)f2bf(a2 * inv) | ((unsigned)f2bf(a3 * inv) << 16);
            __builtin_nontemporal_store(o,
                (uint2v*)(A + (size_t)(node0 + nl) * KTOT + r * IN_F) + fl);
        }
    }
}

// ---------------- fallback-path kernels (small workspace) ----------------
__global__ __launch_bounds__(256) void bucket_fill_kernel(
    const int* __restrict__ src,
    const int* __restrict__ dst,
    int* __restrict__ cnt,
    ushort_t* __restrict__ bucket,
    int nedges)
{
    int e = blockIdx.x * 256 + threadIdx.x;
    if (e >= nedges) return;
    int d = dst[e];
    int pos = atomicAdd(&cnt[d], 1);
    if (pos < CAP)
        bucket[(size_t)d * CAP + pos] = (ushort_t)src[e];
}

__global__ __launch_bounds__(256) void gather_mean_fb_kernel(
    const float* __restrict__ x,
    const int* __restrict__ cnt,
    const ushort_t* __restrict__ bucket,
    ushort_t* __restrict__ A)
{
    int wv = (blockIdx.x * 256 + threadIdx.x) >> 6;
    if (wv >= N_NODES) return;
    int lane = threadIdx.x & 63;
    int c  = cnt[wv];
    int cc = min(c, CAP);
    int sid = (lane < cc) ? (int)bucket[(size_t)wv * CAP + lane] : 0;

    float ax = 0.f, ay = 0.f, bx = 0.f, by = 0.f;
    int e = 0;
    for (; e + 2 <= cc; e += 2) {
        int s0 = __shfl(sid, e);
        int s1 = __shfl(sid, e + 1);
        const float2 v0 = *(const float2*)(x + (size_t)s0 * IN_F + lane * 2);
        const float2 v1 = *(const float2*)(x + (size_t)s1 * IN_F + lane * 2);
        ax += v0.x; ay += v0.y;
        bx += v1.x; by += v1.y;
    }
    if (e < cc) {
        int s0 = __shfl(sid, e);
        const float2 v0 = *(const float2*)(x + (size_t)s0 * IN_F + lane * 2);
        ax += v0.x; ay += v0.y;
    }
    const float inv = 1.0f / fmaxf((float)c, 1.0f);
    unsigned lo = f2bf((ax + bx) * inv);
    unsigned hi = f2bf((ay + by) * inv);
    ((unsigned*)(A + (size_t)wv * IN_F))[lane] = lo | (hi << 16);
}

// C[rows x 128] (+)= A[rows x K]_bf16 @ B (BT stored [128][KTOT]).
// Block 256 = 4 waves; tile 64 rows x 128 cols; wave = 32 rows x 64 cols.
template <int K, int LDA>
__global__ __launch_bounds__(256) void gemm_mfma_kernel(
    const ushort_t* __restrict__ A,
    const ushort_t* __restrict__ BT, int kbase,
    float* __restrict__ out, const float* __restrict__ bias,
    int first, int last)
{
    int tid  = threadIdx.x;
    int wave = tid >> 6, lane = tid & 63;
    int rowf = lane & 15, kg = lane >> 4;
    int rbase = blockIdx.x * 64 + (wave & 1) * 32;
    int cbase = (wave >> 1) * 64;

    f32x4 acc[2][4];
#pragma unroll
    for (int t = 0; t < 2; ++t)
#pragma unroll
        for (int c = 0; c < 4; ++c) acc[t][c] = (f32x4){0.f, 0.f, 0.f, 0.f};

    const short8* Ar0 = (const short8*)(A + (size_t)(rbase + rowf) * LDA + kg * 8);
    const short8* Ar1 = (const short8*)(A + (size_t)(rbase + 16 + rowf) * LDA + kg * 8);
    const ushort_t* Bb = BT + (size_t)(cbase + rowf) * KTOT + kbase + kg * 8;

    short8 a0 = __builtin_nontemporal_load(Ar0);
    short8 a1 = __builtin_nontemporal_load(Ar1);
    short8 b0 = *(const short8*)(Bb);
    short8 b1 = *(const short8*)(Bb + 16 * KTOT);
    short8 b2 = *(const short8*)(Bb + 32 * KTOT);
    short8 b3 = *(const short8*)(Bb + 48 * KTOT);

#pragma unroll
    for (int k0 = 0; k0 < K; k0 += 32) {
        short8 na0 = a0, na1 = a1, nb0 = b0, nb1 = b1, nb2 = b2, nb3 = b3;
        if (k0 + 32 < K) {
            int kk = (k0 + 32) / 8;                   // in short8 units
            na0 = __builtin_nontemporal_load(Ar0 + kk);
            na1 = __builtin_nontemporal_load(Ar1 + kk);
            nb0 = *(const short8*)(Bb + k0 + 32);
            nb1 = *(const short8*)(Bb + 16 * KTOT + k0 + 32);
            nb2 = *(const short8*)(Bb + 32 * KTOT + k0 + 32);
            nb3 = *(const short8*)(Bb + 48 * KTOT + k0 + 32);
        }
        acc[0][0] = __builtin_amdgcn_mfma_f32_16x16x32_bf16(a0, b0, acc[0][0], 0, 0, 0);
        acc[1][0] = __builtin_amdgcn_mfma_f32_16x16x32_bf16(a1, b0, acc[1][0], 0, 0, 0);
        acc[0][1] = __builtin_amdgcn_mfma_f32_16x16x32_bf16(a0, b1, acc[0][1], 0, 0, 0);
        acc[1][1] = __builtin_amdgcn_mfma_f32_16x16x32_bf16(a1, b1, acc[1][1], 0, 0, 0);
        acc[0][2] = __builtin_amdgcn_mfma_f32_16x16x32_bf16(a0, b2, acc[0][2], 0, 0, 0);
        acc[1][2] = __builtin_amdgcn_mfma_f32_16x16x32_bf16(a1, b2, acc[1][2], 0, 0, 0);
        acc[0][3] = __builtin_amdgcn_mfma_f32_16x16x32_bf16(a0, b3, acc[0][3], 0, 0, 0);
        acc[1][3] = __builtin_amdgcn_mfma_f32_16x16x32_bf16(a1, b3, acc[1][3], 0, 0, 0);
        a0 = na0; a1 = na1; b0 = nb0; b1 = nb1; b2 = nb2; b3 = nb3;
    }

    // C/D layout: col = lane&15, row = (lane>>4)*4 + j
#pragma unroll
    for (int t = 0; t < 2; ++t) {
#pragma unroll
        for (int c = 0; c < 4; ++c) {
            int col = cbase + c * 16 + rowf;
#pragma unroll
            for (int j = 0; j < 4; ++j) {
                int row = rbase + t * 16 + kg * 4 + j;
                if (row < N_NODES) {
                    float v = acc[t][c][j];
                    float* p = out + (size_t)row * OUT_F + col;
                    if (!first) v += *p;
                    if (last)  v = fmaxf(v + bias[col], 0.f);
                    *p = v;
                }
            }
        }
    }
}

extern "C" void kernel_launch(void* const* d_in, const int* in_sizes, int n_in,
                              void* d_out, int out_size, void* d_ws, size_t ws_size,
                              hipStream_t stream) {
    const float* x      = (const float*)d_in[0];
    const float* weight = (const float*)d_in[1];
    const float* w_comp = (const float*)d_in[2];
    const float* h_bias = (const float*)d_in[3];
    const int*   src    = (const int*)d_in[4];
    const int*   dst    = (const int*)d_in[5];
    float* out = (float*)d_out;

    char* wsb = (char*)d_ws;
    const size_t btSz    = (size_t)OUT_F * KTOT * 2;               // 256 KB
    const size_t histSz  = (size_t)G_PART * NBIN * 4;              // 800 KB
    const size_t bbaseSz = (size_t)((N_REL * NBIN + 1) * 4 + 255) & ~(size_t)255;
    const size_t bbufSz  = (size_t)N_REL * N_EDGES * 4;            // 25.6 MB
    const size_t aSz     = (size_t)NPAD * KTOT * 2;                // 102.5 MB
    const size_t xbSz    = (size_t)N_NODES * 64 * 4;               // 12.8 MB
    const size_t need    = btSz + histSz + bbaseSz + bbufSz + aSz + xbSz; // ~142 MB

    ushort_t* BT = (ushort_t*)wsb;

    if (ws_size >= need) {
        size_t off = btSz;
        int*      hists   = (int*)(wsb + off);      off += histSz;
        int*      binbase = (int*)(wsb + off);      off += bbaseSz;
        unsigned* binbuf  = (unsigned*)(wsb + off); off += bbufSz;
        ushort_t* A       = (ushort_t*)(wsb + off); off += aSz;
        unsigned* xb      = (unsigned*)(wsb + off);

        prep_fused_kernel<<<G_PART + G_XB + G_WS, 256, 0, stream>>>(
            weight, w_comp, (const float4*)x, (const int4v*)dst,
            BT, (uint2*)xb, hists);
        scan2_kernel<<<N_REL, 1024, 0, stream>>>(hists, binbase);
        place_part_kernel<<<G_PART, 256, 0, stream>>>(
            (const int4v*)src, (const int4v*)dst, hists, binbase, binbuf);
        sort_gather_kernel<<<N_REL * NBIN, 256, 0, stream>>>(
            binbuf, binbase, (const uint2*)xb, A);
        gemm_mfma_kernel<KTOT, KTOT><<<NPAD / 64, 256, 0, stream>>>(
            A, BT, 0, out, h_bias, 1, 1);
    } else {
        // per-relation fallback (~19.7 MB)
        const size_t cntSz1 = (size_t)N_NODES * 4;
        const size_t bktSz1 = (size_t)N_NODES * CAP * 2;
        int*      cnt    = (int*)(wsb + btSz);
        ushort_t* bucket = (ushort_t*)(wsb + btSz + cntSz1);
        ushort_t* A      = (ushort_t*)(wsb + btSz + cntSz1 + bktSz1);

        ws_only_kernel<<<G_WS, 256, 0, stream>>>(weight, w_comp, BT);
        for (int r = 0; r < N_REL; ++r) {
            hipMemsetAsync(cnt, 0, cntSz1, stream);
            bucket_fill_kernel<<<(N_EDGES + 255) / 256, 256, 0, stream>>>(
                src + (size_t)r * N_EDGES, dst + (size_t)r * N_EDGES,
                cnt, bucket, N_EDGES);
            gather_mean_fb_kernel<<<(N_NODES * 64 + 255) / 256, 256, 0, stream>>>(
                x, cnt, bucket, A);
            gemm_mfma_kernel<IN_F, IN_F><<<NPAD / 64, 256, 0, stream>>>(
                A, BT, r * IN_F, out, h_bias, r == 0, r == N_REL - 1);
        }
    }
}

// Round 13
// 400.825 us; speedup vs baseline: 2.2961x; 1.0356x over previous
//
#include <hip/hip_runtime.h>

#define N_NODES  50000
#define NPAD     50048          // 782 * 64
#define IN_F     128
#define OUT_F    128
#define N_REL    8
#define N_BASES  4
#define N_EDGES  800000
#define E4       (N_EDGES / 4)  // 200000
#define KTOT     (N_REL * IN_F) // 1024
#define CAP      64             // fallback per-node bucket cap
#define NBIN     782            // bins of 64 nodes per relation
#define NPART    64             // partition blocks per relation
#define EPART4   (E4 / NPART)   // 3125 int4 per partition block
#define SORTCAP  1536           // Poisson(1024) + 16 sigma

// prep_fused block-range split
#define G_PART   (N_REL * NPART)   // 512
#define G_XB     6250              // N*IN_F/4/256
#define G_WS     512               // 128*1024/256

typedef unsigned short ushort_t;
typedef __attribute__((ext_vector_type(8))) short short8;
typedef __attribute__((ext_vector_type(4))) float f32x4;
typedef __attribute__((ext_vector_type(4))) int  int4v;
typedef __attribute__((ext_vector_type(2))) unsigned uint2v;

__device__ inline ushort_t f2bf(float f) {
    unsigned u = __float_as_uint(f);
    return (ushort_t)((u + 0x7fffu + ((u >> 16) & 1u)) >> 16);   // RNE
}
__device__ inline float bflo(unsigned v) { return __uint_as_float(v << 16); }
__device__ inline float bfhi(unsigned v) { return __uint_as_float(v & 0xffff0000u); }

__device__ inline void ws_body(const float* __restrict__ weight,
                               const float* __restrict__ w_comp,
                               ushort_t* __restrict__ BT, int idx)
{
    int o  = idx >> 10;
    int ri = idx & 1023;
    int r  = ri >> 7;
    int i  = ri & 127;
    float acc = 0.f;
#pragma unroll
    for (int b = 0; b < N_BASES; ++b)
        acc += w_comp[r * N_BASES + b] * weight[b * (IN_F * OUT_F) + i * OUT_F + o];
    BT[idx] = f2bf(acc);
}

// Fused prep: [0,G_PART) per-chunk LDS histograms over bins (no atomics to
// global, contiguous 3KB row writes), [G_PART,+G_XB) x->bf16, [..,+G_WS) BT.
// Mapping r = bid&7, blk = bid>>3: adjacent chunks of one relation sit on the
// SAME XCD (bid%8 -> XCD round-robin), matching place_part's window layout.
__global__ __launch_bounds__(256) void prep_fused_kernel(
    const float* __restrict__ weight,
    const float* __restrict__ w_comp,
    const float4* __restrict__ x4,
    const int4v* __restrict__ dst4,
    ushort_t* __restrict__ BT,
    uint2* __restrict__ xb,
    int* __restrict__ hists)           // [8*NPART][NBIN]
{
    int bid = blockIdx.x;
    if (bid < G_PART) {
        __shared__ int h[NBIN];
        int r = bid & 7, blk = bid >> 3;
        for (int i = threadIdx.x; i < NBIN; i += 256) h[i] = 0;
        __syncthreads();
        const int4v* d4 = dst4 + (size_t)r * E4 + (size_t)blk * EPART4;
        for (int i = threadIdx.x; i < EPART4; i += 256) {
            int4v d = __builtin_nontemporal_load(&d4[i]);
            atomicAdd(&h[d.x >> 6], 1);
            atomicAdd(&h[d.y >> 6], 1);
            atomicAdd(&h[d.z >> 6], 1);
            atomicAdd(&h[d.w >> 6], 1);
        }
        __syncthreads();
        int* hrow = hists + (size_t)(r * NPART + blk) * NBIN;
        for (int i = threadIdx.x; i < NBIN; i += 256) hrow[i] = h[i];
    } else if (bid < G_PART + G_XB) {
        int i = (bid - G_PART) * 256 + threadIdx.x;   // over N*IN_F/4 exact
        float4 v = x4[i];
        uint2 p;
        p.x = (unsigned)f2bf(v.x) | ((unsigned)f2bf(v.y) << 16);
        p.y = (unsigned)f2bf(v.z) | ((unsigned)f2bf(v.w) << 16);
        xb[i] = p;
    } else {
        ws_body(weight, w_comp, BT, (bid - G_PART - G_XB) * 256 + threadIdx.x);
    }
}

// Standalone ws kernel (fallback path)
__global__ __launch_bounds__(256) void ws_only_kernel(
    const float* __restrict__ weight,
    const float* __restrict__ w_comp,
    ushort_t* __restrict__ BT)
{
    ws_body(weight, w_comp, BT, blockIdx.x * 256 + threadIdx.x);
}

// One block per relation (1024 thr): (a) column-scan the NPART block-histograms
// per bin in-place -> per-block local offsets, totals in LDS; (b) block-scan
// the 782 bin totals -> absolute bin bases in binbuf (+ sentinel).
__global__ __launch_bounds__(1024) void scan2_kernel(
    int* __restrict__ hists,           // [8][NPART][NBIN], in-place -> local offs
    int* __restrict__ binbase)         // [8*NBIN + 1]
{
    __shared__ int tot[NBIN];
    __shared__ int wsum[16];
    int r = blockIdx.x, t = threadIdx.x;
    if (t < NBIN) {
        int run = 0;
        int* col = hists + (size_t)r * NPART * NBIN + t;
#pragma unroll 8
        for (int blk = 0; blk < NPART; ++blk) {
            int v = col[(size_t)blk * NBIN];
            col[(size_t)blk * NBIN] = run;
            run += v;
        }
        tot[t] = run;
    }
    __syncthreads();
    int lane = t & 63, wid = t >> 6;
    int v = (t < NBIN) ? tot[t] : 0;
    int inc = v;
#pragma unroll
    for (int off = 1; off < 64; off <<= 1) {
        int u = __shfl_up(inc, off);
        if (lane >= off) inc += u;
    }
    if (lane == 63) wsum[wid] = inc;
    __syncthreads();
    if (t < 16) {
        int iw = wsum[t];
#pragma unroll
        for (int off = 1; off < 16; off <<= 1) {
            int u = __shfl_up(iw, off, 16);
            if (t >= off) iw += u;
        }
        wsum[t] = iw;
    }
    __syncthreads();
    int base = (wid == 0) ? 0 : wsum[wid - 1];
    if (t < NBIN) binbase[r * NBIN + t] = r * N_EDGES + base + inc - v;
    if (r == N_REL - 1 && t == 0) binbase[N_REL * NBIN] = N_REL * N_EDGES;
}

// Each block streams its chunk into its PRIVATE windows of binbuf (cursor =
// binbase + its local offset). No global atomics. r = bid&7, blk = bid>>3:
// blocks with adjacent windows (blk, blk+1 of same r) are 8 bids apart ->
// same XCD, so window-boundary line sharing stays inside one coherent L2.
__global__ __launch_bounds__(256) void place_part_kernel(
    const int4v* __restrict__ src4,
    const int4v* __restrict__ dst4,
    const int* __restrict__ hists,     // local offsets after scan2
    const int* __restrict__ binbase,
    unsigned* __restrict__ binbuf)
{
    __shared__ int cur[NBIN];
    int bid = blockIdx.x;
    int r = bid & 7, blk = bid >> 3;
    const int* hrow = hists + (size_t)(r * NPART + blk) * NBIN;
    const int* bb   = binbase + r * NBIN;
    for (int i = threadIdx.x; i < NBIN; i += 256)
        cur[i] = bb[i] + hrow[i];
    __syncthreads();
    const int4v* s4 = src4 + (size_t)r * E4 + (size_t)blk * EPART4;
    const int4v* d4 = dst4 + (size_t)r * E4 + (size_t)blk * EPART4;
    for (int i = threadIdx.x; i < EPART4; i += 256) {
        int4v s = __builtin_nontemporal_load(&s4[i]);
        int4v d = __builtin_nontemporal_load(&d4[i]);
#define PUT(DV, SV) { int pos = atomicAdd(&cur[(DV) >> 6], 1);                \
        binbuf[pos] = (unsigned)(SV) | ((unsigned)((DV) & 63) << 16); }
        PUT(d.x, s.x) PUT(d.y, s.y) PUT(d.z, s.z) PUT(d.w, s.w)
#undef PUT
    }
}

// Fused sort+gather: one block per (r,bin). (1) load the bin's window to LDS,
// LDS-histogram + counting-sort by local node. (2) each of the 4 waves
// gathers 16 nodes, reading edge lists from LDS srt[]. Half-wave pairing,
// uint2 (8B) feature loads, all cross-lane ops fully converged (R10 lesson).
// A written nontemporally so the 102.5 MB stream doesn't evict xb from L2.
__global__ __launch_bounds__(256) void sort_gather_kernel(
    const unsigned* __restrict__ binbuf,
    const int* __restrict__ binbase,
    const uint2* __restrict__ xb2,     // [N][32] uint2 (bf16-pair rows)
    ushort_t* __restrict__ A)          // [NPAD][KTOT]
{
    __shared__ unsigned ent[SORTCAP];  // 6 KB
    __shared__ ushort_t srt[SORTCAP];  // 3 KB
    __shared__ int h[64], scur[64], sbeg[64];

    int gb  = blockIdx.x;              // r*NBIN + bin
    int r   = gb / NBIN;
    int bin = gb - r * NBIN;
    int t = threadIdx.x;
    int base = binbase[gb];
    int cb = min(binbase[gb + 1] - base, SORTCAP);

    if (t < 64) h[t] = 0;
    __syncthreads();
    for (int i = t; i < cb; i += 256) {
        unsigned e = __builtin_nontemporal_load(&binbuf[(size_t)base + i]);
        ent[i] = e;
        atomicAdd(&h[e >> 16], 1);
    }
    __syncthreads();
    if (t < 64) {                      // wave 0: scan 64 node counts
        int v = h[t];
        int inc = v;
#pragma unroll
        for (int off = 1; off < 64; off <<= 1) {
            int u = __shfl_up(inc, off);
            if (t >= off) inc += u;
        }
        scur[t] = inc - v;
        sbeg[t] = inc - v;
    }
    __syncthreads();
    for (int i = t; i < cb; i += 256) {
        unsigned e = ent[i];
        int p = atomicAdd(&scur[e >> 16], 1);
        srt[p] = (ushort_t)(e & 0xFFFFu);
    }
    __syncthreads();

    // ---- gather phase ----
    int wv = t >> 6, lane = t & 63;
    int hf = lane >> 5;                // half: 0 = even edge, 1 = odd edge
    int fl = lane & 31;                // feature uint2 index
    int node0 = bin * 64;

    for (int k = 0; k < 16; ++k) {
        int nl  = wv * 16 + k;
        int c   = h[nl];
        int off = sbeg[nl];
        float a0 = 0.f, a1 = 0.f, a2 = 0.f, a3 = 0.f;
        for (int bse = 0; bse < c; bse += 64) {
            int m = min(c - bse, 64);  // wave-uniform
            int sid = (lane < m) ? (int)srt[off + bse + lane] : 0;
            int e = 0;
            for (; e + 8 <= m; e += 8) {
                int i0 = __shfl(sid, e + 0 + hf);
                int i1 = __shfl(sid, e + 2 + hf);
                int i2 = __shfl(sid, e + 4 + hf);
                int i3 = __shfl(sid, e + 6 + hf);
                uint2 v0 = xb2[(size_t)i0 * 32 + fl];
                uint2 v1 = xb2[(size_t)i1 * 32 + fl];
                uint2 v2 = xb2[(size_t)i2 * 32 + fl];
                uint2 v3 = xb2[(size_t)i3 * 32 + fl];
                a0 += bflo(v0.x); a1 += bfhi(v0.x); a2 += bflo(v0.y); a3 += bfhi(v0.y);
                a0 += bflo(v1.x); a1 += bfhi(v1.x); a2 += bflo(v1.y); a3 += bfhi(v1.y);
                a0 += bflo(v2.x); a1 += bfhi(v2.x); a2 += bflo(v2.y); a3 += bfhi(v2.y);
                a0 += bflo(v3.x); a1 += bfhi(v3.x); a2 += bflo(v3.y); a3 += bfhi(v3.y);
            }
            for (; e + 2 <= m; e += 2) {
                int i0 = __shfl(sid, e + hf);
                uint2 v0 = xb2[(size_t)i0 * 32 + fl];
                a0 += bflo(v0.x); a1 += bfhi(v0.x); a2 += bflo(v0.y); a3 += bfhi(v0.y);
            }
            if (e < m) {               // uniform branch; shfl fully converged
                int i0 = __shfl(sid, e);
                if (hf == 0) {
                    uint2 v0 = xb2[(size_t)i0 * 32 + fl];
                    a0 += bflo(v0.x); a1 += bfhi(v0.x);
                    a2 += bflo(v0.y); a3 += bfhi(v0.y);
                }
            }
        }
        a0 += __shfl_xor(a0, 32);
        a1 += __shfl_xor(a1, 32);
        a2 += __shfl_xor(a2, 32);
        a3 += __shfl_xor(a3, 32);

        if (hf == 0) {
            const float inv = 1.0f / fmaxf((float)c, 1.0f);
            uint2v o;
            o.x = (unsigned)f2bf(a0 * inv) | ((unsigned)f2bf(a1 * inv) << 16);
            o.y = (unsigned)f2bf(a2 * inv) | ((unsigned)f2bf(a3 * inv) << 16);
            __builtin_nontemporal_store(o,
                (uint2v*)(A + (size_t)(node0 + nl) * KTOT + r * IN_F) + fl);
        }
    }
}

// ---------------- fallback-path kernels (small workspace) ----------------
__global__ __launch_bounds__(256) void bucket_fill_kernel(
    const int* __restrict__ src,
    const int* __restrict__ dst,
    int* __restrict__ cnt,
    ushort_t* __restrict__ bucket,
    int nedges)
{
    int e = blockIdx.x * 256 + threadIdx.x;
    if (e >= nedges) return;
    int d = dst[e];
    int pos = atomicAdd(&cnt[d], 1);
    if (pos < CAP)
        bucket[(size_t)d * CAP + pos] = (ushort_t)src[e];
}

__global__ __launch_bounds__(256) void gather_mean_fb_kernel(
    const float* __restrict__ x,
    const int* __restrict__ cnt,
    const ushort_t* __restrict__ bucket,
    ushort_t* __restrict__ A)
{
    int wv = (blockIdx.x * 256 + threadIdx.x) >> 6;
    if (wv >= N_NODES) return;
    int lane = threadIdx.x & 63;
    int c  = cnt[wv];
    int cc = min(c, CAP);
    int sid = (lane < cc) ? (int)bucket[(size_t)wv * CAP + lane] : 0;

    float ax = 0.f, ay = 0.f, bx = 0.f, by = 0.f;
    int e = 0;
    for (; e + 2 <= cc; e += 2) {
        int s0 = __shfl(sid, e);
        int s1 = __shfl(sid, e + 1);
        const float2 v0 = *(const float2*)(x + (size_t)s0 * IN_F + lane * 2);
        const float2 v1 = *(const float2*)(x + (size_t)s1 * IN_F + lane * 2);
        ax += v0.x; ay += v0.y;
        bx += v1.x; by += v1.y;
    }
    if (e < cc) {
        int s0 = __shfl(sid, e);
        const float2 v0 = *(const float2*)(x + (size_t)s0 * IN_F + lane * 2);
        ax += v0.x; ay += v0.y;
    }
    const float inv = 1.0f / fmaxf((float)c, 1.0f);
    unsigned lo = f2bf((ax + bx) * inv);
    unsigned hi = f2bf((ay + by) * inv);
    ((unsigned*)(A + (size_t)wv * IN_F))[lane] = lo | (hi << 16);
}

// C[rows x 128] (+)= A[rows x K]_bf16 @ B (BT stored [128][KTOT]).
// Block 256 = 4 waves; tile 64 rows x 128 cols; wave = 32 rows x 64 cols.
template <int K, int LDA>
__global__ __launch_bounds__(256) void gemm_mfma_kernel(
    const ushort_t* __restrict__ A,
    const ushort_t* __restrict__ BT, int kbase,
    float* __restrict__ out, const float* __restrict__ bias,
    int first, int last)
{
    int tid  = threadIdx.x;
    int wave = tid >> 6, lane = tid & 63;
    int rowf = lane & 15, kg = lane >> 4;
    int rbase = blockIdx.x * 64 + (wave & 1) * 32;
    int cbase = (wave >> 1) * 64;

    f32x4 acc[2][4];
#pragma unroll
    for (int t = 0; t < 2; ++t)
#pragma unroll
        for (int c = 0; c < 4; ++c) acc[t][c] = (f32x4){0.f, 0.f, 0.f, 0.f};

    const short8* Ar0 = (const short8*)(A + (size_t)(rbase + rowf) * LDA + kg * 8);
    const short8* Ar1 = (const short8*)(A + (size_t)(rbase + 16 + rowf) * LDA + kg * 8);
    const ushort_t* Bb = BT + (size_t)(cbase + rowf) * KTOT + kbase + kg * 8;

    short8 a0 = __builtin_nontemporal_load(Ar0);
    short8 a1 = __builtin_nontemporal_load(Ar1);
    short8 b0 = *(const short8*)(Bb);
    short8 b1 = *(const short8*)(Bb + 16 * KTOT);
    short8 b2 = *(const short8*)(Bb + 32 * KTOT);
    short8 b3 = *(const short8*)(Bb + 48 * KTOT);

#pragma unroll
    for (int k0 = 0; k0 < K; k0 += 32) {
        short8 na0 = a0, na1 = a1, nb0 = b0, nb1 = b1, nb2 = b2, nb3 = b3;
        if (k0 + 32 < K) {
            int kk = (k0 + 32) / 8;                   // in short8 units
            na0 = __builtin_nontemporal_load(Ar0 + kk);
            na1 = __builtin_nontemporal_load(Ar1 + kk);
            nb0 = *(const short8*)(Bb + k0 + 32);
            nb1 = *(const short8*)(Bb + 16 * KTOT + k0 + 32);
            nb2 = *(const short8*)(Bb + 32 * KTOT + k0 + 32);
            nb3 = *(const short8*)(Bb + 48 * KTOT + k0 + 32);
        }
        acc[0][0] = __builtin_amdgcn_mfma_f32_16x16x32_bf16(a0, b0, acc[0][0], 0, 0, 0);
        acc[1][0] = __builtin_amdgcn_mfma_f32_16x16x32_bf16(a1, b0, acc[1][0], 0, 0, 0);
        acc[0][1] = __builtin_amdgcn_mfma_f32_16x16x32_bf16(a0, b1, acc[0][1], 0, 0, 0);
        acc[1][1] = __builtin_amdgcn_mfma_f32_16x16x32_bf16(a1, b1, acc[1][1], 0, 0, 0);
        acc[0][2] = __builtin_amdgcn_mfma_f32_16x16x32_bf16(a0, b2, acc[0][2], 0, 0, 0);
        acc[1][2] = __builtin_amdgcn_mfma_f32_16x16x32_bf16(a1, b2, acc[1][2], 0, 0, 0);
        acc[0][3] = __builtin_amdgcn_mfma_f32_16x16x32_bf16(a0, b3, acc[0][3], 0, 0, 0);
        acc[1][3] = __builtin_amdgcn_mfma_f32_16x16x32_bf16(a1, b3, acc[1][3], 0, 0, 0);
        a0 = na0; a1 = na1; b0 = nb0; b1 = nb1; b2 = nb2; b3 = nb3;
    }

    // C/D layout: col = lane&15, row = (lane>>4)*4 + j
#pragma unroll
    for (int t = 0; t < 2; ++t) {
#pragma unroll
        for (int c = 0; c < 4; ++c) {
            int col = cbase + c * 16 + rowf;
#pragma unroll
            for (int j = 0; j < 4; ++j) {
                int row = rbase + t * 16 + kg * 4 + j;
                if (row < N_NODES) {
                    float v = acc[t][c][j];
                    float* p = out + (size_t)row * OUT_F + col;
                    if (!first) v += *p;
                    if (last)  v = fmaxf(v + bias[col], 0.f);
                    *p = v;
                }
            }
        }
    }
}

extern "C" void kernel_launch(void* const* d_in, const int* in_sizes, int n_in,
                              void* d_out, int out_size, void* d_ws, size_t ws_size,
                              hipStream_t stream) {
    const float* x      = (const float*)d_in[0];
    const float* weight = (const float*)d_in[1];
    const float* w_comp = (const float*)d_in[2];
    const float* h_bias = (const float*)d_in[3];
    const int*   src    = (const int*)d_in[4];
    const int*   dst    = (const int*)d_in[5];
    float* out = (float*)d_out;

    char* wsb = (char*)d_ws;
    const size_t btSz    = (size_t)OUT_F * KTOT * 2;               // 256 KB
    const size_t histSz  = (size_t)G_PART * NBIN * 4;              // 1.6 MB
    const size_t bbaseSz = (size_t)((N_REL * NBIN + 1) * 4 + 255) & ~(size_t)255;
    const size_t bbufSz  = (size_t)N_REL * N_EDGES * 4;            // 25.6 MB
    const size_t aSz     = (size_t)NPAD * KTOT * 2;                // 102.5 MB
    const size_t xbSz    = (size_t)N_NODES * 64 * 4;               // 12.8 MB
    const size_t need    = btSz + histSz + bbaseSz + bbufSz + aSz + xbSz; // ~143 MB

    ushort_t* BT = (ushort_t*)wsb;

    if (ws_size >= need) {
        size_t off = btSz;
        int*      hists   = (int*)(wsb + off);      off += histSz;
        int*      binbase = (int*)(wsb + off);      off += bbaseSz;
        unsigned* binbuf  = (unsigned*)(wsb + off); off += bbufSz;
        ushort_t* A       = (ushort_t*)(wsb + off); off += aSz;
        unsigned* xb      = (unsigned*)(wsb + off);

        prep_fused_kernel<<<G_PART + G_XB + G_WS, 256, 0, stream>>>(
            weight, w_comp, (const float4*)x, (const int4v*)dst,
            BT, (uint2*)xb, hists);
        scan2_kernel<<<N_REL, 1024, 0, stream>>>(hists, binbase);
        place_part_kernel<<<G_PART, 256, 0, stream>>>(
            (const int4v*)src, (const int4v*)dst, hists, binbase, binbuf);
        sort_gather_kernel<<<N_REL * NBIN, 256, 0, stream>>>(
            binbuf, binbase, (const uint2*)xb, A);
        gemm_mfma_kernel<KTOT, KTOT><<<NPAD / 64, 256, 0, stream>>>(
            A, BT, 0, out, h_bias, 1, 1);
    } else {
        // per-relation fallback (~19.7 MB)
        const size_t cntSz1 = (size_t)N_NODES * 4;
        const size_t bktSz1 = (size_t)N_NODES * CAP * 2;
        int*      cnt    = (int*)(wsb + btSz);
        ushort_t* bucket = (ushort_t*)(wsb + btSz + cntSz1);
        ushort_t* A      = (ushort_t*)(wsb + btSz + cntSz1 + bktSz1);

        ws_only_kernel<<<G_WS, 256, 0, stream>>>(weight, w_comp, BT);
        for (int r = 0; r < N_REL; ++r) {
            hipMemsetAsync(cnt, 0, cntSz1, stream);
            bucket_fill_kernel<<<(N_EDGES + 255) / 256, 256, 0, stream>>>(
                src + (size_t)r * N_EDGES, dst + (size_t)r * N_EDGES,
                cnt, bucket, N_EDGES);
            gather_mean_fb_kernel<<<(N_NODES * 64 + 255) / 256, 256, 0, stream>>>(
                x, cnt, bucket, A);
            gemm_mfma_kernel<IN_F, IN_F><<<NPAD / 64, 256, 0, stream>>>(
                A, BT, r * IN_F, out, h_bias, r == 0, r == N_REL - 1);
        }
    }
}

// Round 14
// 334.042 us; speedup vs baseline: 2.7551x; 1.1999x over previous
//
#include <hip/hip_runtime.h>

#define N_NODES  50000
#define NPAD     50048          // 782 * 64
#define IN_F     128
#define OUT_F    128
#define N_REL    8
#define N_BASES  4
#define N_EDGES  800000
#define E4       (N_EDGES / 4)  // 200000
#define KTOT     (N_REL * IN_F) // 1024
#define CAP      64             // fallback per-node bucket cap
#define NBIN     782            // bins of 64 nodes per relation
#define NPART    64             // partition blocks per relation
#define EPART4   (E4 / NPART)   // 3125 int4 per partition block
#define EPART    (EPART4 * 4)   // 12500 edges per partition block
#define SORTCAP  1536           // Poisson(1024) + 16 sigma

// prep_fused block-range split
#define G_PART   (N_REL * NPART)   // 512
#define G_XB     6250              // N*IN_F/4/256
#define G_WS     512               // 128*1024/256

typedef unsigned short ushort_t;
typedef __attribute__((ext_vector_type(8))) short short8;
typedef __attribute__((ext_vector_type(4))) float f32x4;
typedef __attribute__((ext_vector_type(4))) int  int4v;
typedef __attribute__((ext_vector_type(2))) unsigned uint2v;

__device__ inline ushort_t f2bf(float f) {
    unsigned u = __float_as_uint(f);
    return (ushort_t)((u + 0x7fffu + ((u >> 16) & 1u)) >> 16);   // RNE
}
__device__ inline float bflo(unsigned v) { return __uint_as_float(v << 16); }
__device__ inline float bfhi(unsigned v) { return __uint_as_float(v & 0xffff0000u); }

__device__ inline void ws_body(const float* __restrict__ weight,
                               const float* __restrict__ w_comp,
                               ushort_t* __restrict__ BT, int idx)
{
    int o  = idx >> 10;
    int ri = idx & 1023;
    int r  = ri >> 7;
    int i  = ri & 127;
    float acc = 0.f;
#pragma unroll
    for (int b = 0; b < N_BASES; ++b)
        acc += w_comp[r * N_BASES + b] * weight[b * (IN_F * OUT_F) + i * OUT_F + o];
    BT[idx] = f2bf(acc);
}

// Fused prep: [0,G_PART) per-chunk LDS histograms over bins (no atomics to
// global, contiguous 3KB row writes), [G_PART,+G_XB) x->bf16, [..,+G_WS) BT.
__global__ __launch_bounds__(256) void prep_fused_kernel(
    const float* __restrict__ weight,
    const float* __restrict__ w_comp,
    const float4* __restrict__ x4,
    const int4v* __restrict__ dst4,
    ushort_t* __restrict__ BT,
    uint2* __restrict__ xb,
    int* __restrict__ hists)           // [8*NPART][NBIN]  (raw counts)
{
    int bid = blockIdx.x;
    if (bid < G_PART) {
        __shared__ int h[NBIN];
        int r = bid & 7, blk = bid >> 3;
        for (int i = threadIdx.x; i < NBIN; i += 256) h[i] = 0;
        __syncthreads();
        const int4v* d4 = dst4 + (size_t)r * E4 + (size_t)blk * EPART4;
        for (int i = threadIdx.x; i < EPART4; i += 256) {
            int4v d = __builtin_nontemporal_load(&d4[i]);
            atomicAdd(&h[d.x >> 6], 1);
            atomicAdd(&h[d.y >> 6], 1);
            atomicAdd(&h[d.z >> 6], 1);
            atomicAdd(&h[d.w >> 6], 1);
        }
        __syncthreads();
        int* hrow = hists + (size_t)(r * NPART + blk) * NBIN;
        for (int i = threadIdx.x; i < NBIN; i += 256) hrow[i] = h[i];
    } else if (bid < G_PART + G_XB) {
        int i = (bid - G_PART) * 256 + threadIdx.x;   // over N*IN_F/4 exact
        float4 v = x4[i];
        uint2 p;
        p.x = (unsigned)f2bf(v.x) | ((unsigned)f2bf(v.y) << 16);
        p.y = (unsigned)f2bf(v.z) | ((unsigned)f2bf(v.w) << 16);
        xb[i] = p;
    } else {
        ws_body(weight, w_comp, BT, (bid - G_PART - G_XB) * 256 + threadIdx.x);
    }
}

// Standalone ws kernel (fallback path)
__global__ __launch_bounds__(256) void ws_only_kernel(
    const float* __restrict__ weight,
    const float* __restrict__ w_comp,
    ushort_t* __restrict__ BT)
{
    ws_body(weight, w_comp, BT, blockIdx.x * 256 + threadIdx.x);
}

// One block per relation (1024 thr): (a) column-scan the NPART block-histograms
// per bin -> per-block local offsets (loffs; hists stays raw), totals in LDS;
// (b) block-scan the 782 bin totals -> absolute bin bases (+ sentinel).
__global__ __launch_bounds__(1024) void scan2_kernel(
    const int* __restrict__ hists,     // [8][NPART][NBIN] raw
    int* __restrict__ loffs,           // [8][NPART][NBIN] local offsets
    int* __restrict__ binbase)         // [8*NBIN + 1]
{
    __shared__ int tot[NBIN];
    __shared__ int wsum[16];
    int r = blockIdx.x, t = threadIdx.x;
    if (t < NBIN) {
        int run = 0;
        const int* col = hists + (size_t)r * NPART * NBIN + t;
        int*       lof = loffs + (size_t)r * NPART * NBIN + t;
#pragma unroll 8
        for (int blk = 0; blk < NPART; ++blk) {
            int v = col[(size_t)blk * NBIN];
            lof[(size_t)blk * NBIN] = run;
            run += v;
        }
        tot[t] = run;
    }
    __syncthreads();
    int lane = t & 63, wid = t >> 6;
    int v = (t < NBIN) ? tot[t] : 0;
    int inc = v;
#pragma unroll
    for (int off = 1; off < 64; off <<= 1) {
        int u = __shfl_up(inc, off);
        if (lane >= off) inc += u;
    }
    if (lane == 63) wsum[wid] = inc;
    __syncthreads();
    if (t < 16) {
        int iw = wsum[t];
#pragma unroll
        for (int off = 1; off < 16; off <<= 1) {
            int u = __shfl_up(iw, off, 16);
            if (t >= off) iw += u;
        }
        wsum[t] = iw;
    }
    __syncthreads();
    int base = (wid == 0) ? 0 : wsum[wid - 1];
    if (t < NBIN) binbase[r * NBIN + t] = r * N_EDGES + base + inc - v;
    if (r == N_REL - 1 && t == 0) binbase[N_REL * NBIN] = N_REL * N_EDGES;
}

// place v2: stage the block's 12500 edges in LDS, counting-sort BY BIN
// (entry packs src:16 | dstLocal:6 | bin:10), then stream the sorted array
// linearly to global — consecutive threads hit consecutive addresses within
// each bin-run, turning 64-way scattered 4B stores into coalesced bursts.
// LDS 56.3 KB -> exactly 2 blocks/CU (512 blocks fully resident).
__global__ __launch_bounds__(256) void place_part_kernel(
    const int4v* __restrict__ src4,
    const int4v* __restrict__ dst4,
    const int* __restrict__ hists,     // raw per-chunk counts
    const int* __restrict__ loffs,     // local offsets from scan2
    const int* __restrict__ binbase,
    unsigned* __restrict__ binbuf)
{
    __shared__ unsigned ent[EPART];    // 50 KB
    __shared__ int scur[NBIN];         // LDS write cursors (start at lds_start)
    __shared__ int dlt[NBIN];          // global_base - lds_start per bin
    __shared__ int wsum[4];

    int bid = blockIdx.x;
    int r = bid & 7, blk = bid >> 3;
    int t = threadIdx.x;
    int lane = t & 63, wid = t >> 6;
    size_t row = (size_t)(r * NPART + blk) * NBIN;
    const int* bb = binbase + r * NBIN;

    // phase 0: block-exclusive-scan of own hist row -> lds_start (scur) + dlt
    int carry = 0;
    for (int chunk = 0; chunk < NBIN; chunk += 256) {
        int i = chunk + t;
        int v = (i < NBIN) ? hists[row + i] : 0;
        int inc = v;
#pragma unroll
        for (int off = 1; off < 64; off <<= 1) {
            int u = __shfl_up(inc, off);
            if (lane >= off) inc += u;
        }
        if (lane == 63) wsum[wid] = inc;
        __syncthreads();
        if (t < 4) {
            int iw = wsum[t];
#pragma unroll
            for (int off = 1; off < 4; off <<= 1) {
                int u = __shfl_up(iw, off, 4);
                if (t >= off) iw += u;
            }
            wsum[t] = iw;
        }
        __syncthreads();
        int base = (wid == 0) ? 0 : wsum[wid - 1];
        int excl = carry + base + inc - v;
        if (i < NBIN) {
            scur[i] = excl;
            dlt[i]  = bb[i] + loffs[row + i] - excl;
        }
        int total = wsum[3];
        __syncthreads();
        carry += total;
    }

    // phase 1: scatter edges into LDS, sorted by bin
    const int4v* s4 = src4 + (size_t)r * E4 + (size_t)blk * EPART4;
    const int4v* d4 = dst4 + (size_t)r * E4 + (size_t)blk * EPART4;
    for (int i = t; i < EPART4; i += 256) {
        int4v s = __builtin_nontemporal_load(&s4[i]);
        int4v d = __builtin_nontemporal_load(&d4[i]);
#define PUT(DV, SV) { int b = (DV) >> 6;                                      \
        int p = atomicAdd(&scur[b], 1);                                       \
        ent[p] = (unsigned)(SV) | ((unsigned)((DV) & 63) << 16)               \
               | ((unsigned)b << 22); }
        PUT(d.x, s.x) PUT(d.y, s.y) PUT(d.z, s.z) PUT(d.w, s.w)
#undef PUT
    }
    __syncthreads();

    // phase 2: linear stream-out; addr = dlt[bin] + p is contiguous per run
    for (int p = t; p < EPART; p += 256) {
        unsigned val = ent[p];
        int b = (int)(val >> 22);
        binbuf[dlt[b] + p] = val;
    }
}

// Fused sort+gather: one block per (r,bin). (1) load the bin's window to LDS,
// LDS-histogram + counting-sort by local node. (2) each of the 4 waves
// gathers 16 nodes, reading edge lists from LDS srt[]. Half-wave pairing,
// uint2 (8B) feature loads, all cross-lane ops fully converged (R10 lesson).
// A written nontemporally so the 102.5 MB stream doesn't evict xb from L2.
__global__ __launch_bounds__(256) void sort_gather_kernel(
    const unsigned* __restrict__ binbuf,
    const int* __restrict__ binbase,
    const uint2* __restrict__ xb2,     // [N][32] uint2 (bf16-pair rows)
    ushort_t* __restrict__ A)          // [NPAD][KTOT]
{
    __shared__ unsigned ent[SORTCAP];  // 6 KB
    __shared__ ushort_t srt[SORTCAP];  // 3 KB
    __shared__ int h[64], scur[64], sbeg[64];

    int gb  = blockIdx.x;              // r*NBIN + bin
    int r   = gb / NBIN;
    int bin = gb - r * NBIN;
    int t = threadIdx.x;
    int base = binbase[gb];
    int cb = min(binbase[gb + 1] - base, SORTCAP);

    if (t < 64) h[t] = 0;
    __syncthreads();
    for (int i = t; i < cb; i += 256) {
        unsigned e = __builtin_nontemporal_load(&binbuf[(size_t)base + i]);
        ent[i] = e;
        atomicAdd(&h[(e >> 16) & 63], 1);
    }
    __syncthreads();
    if (t < 64) {                      // wave 0: scan 64 node counts
        int v = h[t];
        int inc = v;
#pragma unroll
        for (int off = 1; off < 64; off <<= 1) {
            int u = __shfl_up(inc, off);
            if (t >= off) inc += u;
        }
        scur[t] = inc - v;
        sbeg[t] = inc - v;
    }
    __syncthreads();
    for (int i = t; i < cb; i += 256) {
        unsigned e = ent[i];
        int p = atomicAdd(&scur[(e >> 16) & 63], 1);
        srt[p] = (ushort_t)(e & 0xFFFFu);
    }
    __syncthreads();

    // ---- gather phase ----
    int wv = t >> 6, lane = t & 63;
    int hf = lane >> 5;                // half: 0 = even edge, 1 = odd edge
    int fl = lane & 31;                // feature uint2 index
    int node0 = bin * 64;

    for (int k = 0; k < 16; ++k) {
        int nl  = wv * 16 + k;
        int c   = h[nl];
        int off = sbeg[nl];
        float a0 = 0.f, a1 = 0.f, a2 = 0.f, a3 = 0.f;
        for (int bse = 0; bse < c; bse += 64) {
            int m = min(c - bse, 64);  // wave-uniform
            int sid = (lane < m) ? (int)srt[off + bse + lane] : 0;
            int e = 0;
            for (; e + 8 <= m; e += 8) {
                int i0 = __shfl(sid, e + 0 + hf);
                int i1 = __shfl(sid, e + 2 + hf);
                int i2 = __shfl(sid, e + 4 + hf);
                int i3 = __shfl(sid, e + 6 + hf);
                uint2 v0 = xb2[(size_t)i0 * 32 + fl];
                uint2 v1 = xb2[(size_t)i1 * 32 + fl];
                uint2 v2 = xb2[(size_t)i2 * 32 + fl];
                uint2 v3 = xb2[(size_t)i3 * 32 + fl];
                a0 += bflo(v0.x); a1 += bfhi(v0.x); a2 += bflo(v0.y); a3 += bfhi(v0.y);
                a0 += bflo(v1.x); a1 += bfhi(v1.x); a2 += bflo(v1.y); a3 += bfhi(v1.y);
                a0 += bflo(v2.x); a1 += bfhi(v2.x); a2 += bflo(v2.y); a3 += bfhi(v2.y);
                a0 += bflo(v3.x); a1 += bfhi(v3.x); a2 += bflo(v3.y); a3 += bfhi(v3.y);
            }
            for (; e + 2 <= m; e += 2) {
                int i0 = __shfl(sid, e + hf);
                uint2 v0 = xb2[(size_t)i0 * 32 + fl];
                a0 += bflo(v0.x); a1 += bfhi(v0.x); a2 += bflo(v0.y); a3 += bfhi(v0.y);
            }
            if (e < m) {               // uniform branch; shfl fully converged
                int i0 = __shfl(sid, e);
                if (hf == 0) {
                    uint2 v0 = xb2[(size_t)i0 * 32 + fl];
                    a0 += bflo(v0.x); a1 += bfhi(v0.x);
                    a2 += bflo(v0.y); a3 += bfhi(v0.y);
                }
            }
        }
        a0 += __shfl_xor(a0, 32);
        a1 += __shfl_xor(a1, 32);
        a2 += __shfl_xor(a2, 32);
        a3 += __shfl_xor(a3, 32);

        if (hf == 0) {
            const float inv = 1.0f / fmaxf((float)c, 1.0f);
            uint2v o;
            o.x = (unsigned)f2bf(a0 * inv) | ((unsigned)f2bf(a1 * inv) << 16);
            o.y = (unsigned)f2bf(a2 * inv) | ((unsigned)f2bf(a3 * inv) << 16);
            __builtin_nontemporal_store(o,
                (uint2v*)(A + (size_t)(node0 + nl) * KTOT + r * IN_F) + fl);
        }
    }
}

// ---------------- fallback-path kernels (small workspace) ----------------
__global__ __launch_bounds__(256) void bucket_fill_kernel(
    const int* __restrict__ src,
    const int* __restrict__ dst,
    int* __restrict__ cnt,
    ushort_t* __restrict__ bucket,
    int nedges)
{
    int e = blockIdx.x * 256 + threadIdx.x;
    if (e >= nedges) return;
    int d = dst[e];
    int pos = atomicAdd(&cnt[d], 1);
    if (pos < CAP)
        bucket[(size_t)d * CAP + pos] = (ushort_t)src[e];
}

__global__ __launch_bounds__(256) void gather_mean_fb_kernel(
    const float* __restrict__ x,
    const int* __restrict__ cnt,
    const ushort_t* __restrict__ bucket,
    ushort_t* __restrict__ A)
{
    int wv = (blockIdx.x * 256 + threadIdx.x) >> 6;
    if (wv >= N_NODES) return;
    int lane = threadIdx.x & 63;
    int c  = cnt[wv];
    int cc = min(c, CAP);
    int sid = (lane < cc) ? (int)bucket[(size_t)wv * CAP + lane] : 0;

    float ax = 0.f, ay = 0.f, bx = 0.f, by = 0.f;
    int e = 0;
    for (; e + 2 <= cc; e += 2) {
        int s0 = __shfl(sid, e);
        int s1 = __shfl(sid, e + 1);
        const float2 v0 = *(const float2*)(x + (size_t)s0 * IN_F + lane * 2);
        const float2 v1 = *(const float2*)(x + (size_t)s1 * IN_F + lane * 2);
        ax += v0.x; ay += v0.y;
        bx += v1.x; by += v1.y;
    }
    if (e < cc) {
        int s0 = __shfl(sid, e);
        const float2 v0 = *(const float2*)(x + (size_t)s0 * IN_F + lane * 2);
        ax += v0.x; ay += v0.y;
    }
    const float inv = 1.0f / fmaxf((float)c, 1.0f);
    unsigned lo = f2bf((ax + bx) * inv);
    unsigned hi = f2bf((ay + by) * inv);
    ((unsigned*)(A + (size_t)wv * IN_F))[lane] = lo | (hi << 16);
}

// C[rows x 128] (+)= A[rows x K]_bf16 @ B (BT stored [128][KTOT]).
// Block 256 = 4 waves; tile 64 rows x 128 cols; wave = 32 rows x 64 cols.
template <int K, int LDA>
__global__ __launch_bounds__(256) void gemm_mfma_kernel(
    const ushort_t* __restrict__ A,
    const ushort_t* __restrict__ BT, int kbase,
    float* __restrict__ out, const float* __restrict__ bias,
    int first, int last)
{
    int tid  = threadIdx.x;
    int wave = tid >> 6, lane = tid & 63;
    int rowf = lane & 15, kg = lane >> 4;
    int rbase = blockIdx.x * 64 + (wave & 1) * 32;
    int cbase = (wave >> 1) * 64;

    f32x4 acc[2][4];
#pragma unroll
    for (int t = 0; t < 2; ++t)
#pragma unroll
        for (int c = 0; c < 4; ++c) acc[t][c] = (f32x4){0.f, 0.f, 0.f, 0.f};

    const short8* Ar0 = (const short8*)(A + (size_t)(rbase + rowf) * LDA + kg * 8);
    const short8* Ar1 = (const short8*)(A + (size_t)(rbase + 16 + rowf) * LDA + kg * 8);
    const ushort_t* Bb = BT + (size_t)(cbase + rowf) * KTOT + kbase + kg * 8;

    short8 a0 = __builtin_nontemporal_load(Ar0);
    short8 a1 = __builtin_nontemporal_load(Ar1);
    short8 b0 = *(const short8*)(Bb);
    short8 b1 = *(const short8*)(Bb + 16 * KTOT);
    short8 b2 = *(const short8*)(Bb + 32 * KTOT);
    short8 b3 = *(const short8*)(Bb + 48 * KTOT);

#pragma unroll
    for (int k0 = 0; k0 < K; k0 += 32) {
        short8 na0 = a0, na1 = a1, nb0 = b0, nb1 = b1, nb2 = b2, nb3 = b3;
        if (k0 + 32 < K) {
            int kk = (k0 + 32) / 8;                   // in short8 units
            na0 = __builtin_nontemporal_load(Ar0 + kk);
            na1 = __builtin_nontemporal_load(Ar1 + kk);
            nb0 = *(const short8*)(Bb + k0 + 32);
            nb1 = *(const short8*)(Bb + 16 * KTOT + k0 + 32);
            nb2 = *(const short8*)(Bb + 32 * KTOT + k0 + 32);
            nb3 = *(const short8*)(Bb + 48 * KTOT + k0 + 32);
        }
        acc[0][0] = __builtin_amdgcn_mfma_f32_16x16x32_bf16(a0, b0, acc[0][0], 0, 0, 0);
        acc[1][0] = __builtin_amdgcn_mfma_f32_16x16x32_bf16(a1, b0, acc[1][0], 0, 0, 0);
        acc[0][1] = __builtin_amdgcn_mfma_f32_16x16x32_bf16(a0, b1, acc[0][1], 0, 0, 0);
        acc[1][1] = __builtin_amdgcn_mfma_f32_16x16x32_bf16(a1, b1, acc[1][1], 0, 0, 0);
        acc[0][2] = __builtin_amdgcn_mfma_f32_16x16x32_bf16(a0, b2, acc[0][2], 0, 0, 0);
        acc[1][2] = __builtin_amdgcn_mfma_f32_16x16x32_bf16(a1, b2, acc[1][2], 0, 0, 0);
        acc[0][3] = __builtin_amdgcn_mfma_f32_16x16x32_bf16(a0, b3, acc[0][3], 0, 0, 0);
        acc[1][3] = __builtin_amdgcn_mfma_f32_16x16x32_bf16(a1, b3, acc[1][3], 0, 0, 0);
        a0 = na0; a1 = na1; b0 = nb0; b1 = nb1; b2 = nb2; b3 = nb3;
    }

    // C/D layout: col = lane&15, row = (lane>>4)*4 + j
#pragma unroll
    for (int t = 0; t < 2; ++t) {
#pragma unroll
        for (int c = 0; c < 4; ++c) {
            int col = cbase + c * 16 + rowf;
#pragma unroll
            for (int j = 0; j < 4; ++j) {
                int row = rbase + t * 16 + kg * 4 + j;
                if (row < N_NODES) {
                    float v = acc[t][c][j];
                    float* p = out + (size_t)row * OUT_F + col;
                    if (!first) v += *p;
                    if (last)  v = fmaxf(v + bias[col], 0.f);
                    *p = v;
                }
            }
        }
    }
}

extern "C" void kernel_launch(void* const* d_in, const int* in_sizes, int n_in,
                              void* d_out, int out_size, void* d_ws, size_t ws_size,
                              hipStream_t stream) {
    const float* x      = (const float*)d_in[0];
    const float* weight = (const float*)d_in[1];
    const float* w_comp = (const float*)d_in[2];
    const float* h_bias = (const float*)d_in[3];
    const int*   src    = (const int*)d_in[4];
    const int*   dst    = (const int*)d_in[5];
    float* out = (float*)d_out;

    char* wsb = (char*)d_ws;
    const size_t btSz    = (size_t)OUT_F * KTOT * 2;               // 256 KB
    const size_t histSz  = (size_t)G_PART * NBIN * 4;              // 1.6 MB
    const size_t bbaseSz = (size_t)((N_REL * NBIN + 1) * 4 + 255) & ~(size_t)255;
    const size_t bbufSz  = (size_t)N_REL * N_EDGES * 4;            // 25.6 MB
    const size_t aSz     = (size_t)NPAD * KTOT * 2;                // 102.5 MB
    const size_t xbSz    = (size_t)N_NODES * 64 * 4;               // 12.8 MB
    const size_t need    = btSz + 2 * histSz + bbaseSz + bbufSz + aSz + xbSz; // ~145 MB

    ushort_t* BT = (ushort_t*)wsb;

    if (ws_size >= need) {
        size_t off = btSz;
        int*      hists   = (int*)(wsb + off);      off += histSz;
        int*      loffs   = (int*)(wsb + off);      off += histSz;
        int*      binbase = (int*)(wsb + off);      off += bbaseSz;
        unsigned* binbuf  = (unsigned*)(wsb + off); off += bbufSz;
        ushort_t* A       = (ushort_t*)(wsb + off); off += aSz;
        unsigned* xb      = (unsigned*)(wsb + off);

        prep_fused_kernel<<<G_PART + G_XB + G_WS, 256, 0, stream>>>(
            weight, w_comp, (const float4*)x, (const int4v*)dst,
            BT, (uint2*)xb, hists);
        scan2_kernel<<<N_REL, 1024, 0, stream>>>(hists, loffs, binbase);
        place_part_kernel<<<G_PART, 256, 0, stream>>>(
            (const int4v*)src, (const int4v*)dst, hists, loffs, binbase, binbuf);
        sort_gather_kernel<<<N_REL * NBIN, 256, 0, stream>>>(
            binbuf, binbase, (const uint2*)xb, A);
        gemm_mfma_kernel<KTOT, KTOT><<<NPAD / 64, 256, 0, stream>>>(
            A, BT, 0, out, h_bias, 1, 1);
    } else {
        // per-relation fallback (~19.7 MB)
        const size_t cntSz1 = (size_t)N_NODES * 4;
        const size_t bktSz1 = (size_t)N_NODES * CAP * 2;
        int*      cnt    = (int*)(wsb + btSz);
        ushort_t* bucket = (ushort_t*)(wsb + btSz + cntSz1);
        ushort_t* A      = (ushort_t*)(wsb + btSz + cntSz1 + bktSz1);

        ws_only_kernel<<<G_WS, 256, 0, stream>>>(weight, w_comp, BT);
        for (int r = 0; r < N_REL; ++r) {
            hipMemsetAsync(cnt, 0, cntSz1, stream);
            bucket_fill_kernel<<<(N_EDGES + 255) / 256, 256, 0, stream>>>(
                src + (size_t)r * N_EDGES, dst + (size_t)r * N_EDGES,
                cnt, bucket, N_EDGES);
            gather_mean_fb_kernel<<<(N_NODES * 64 + 255) / 256, 256, 0, stream>>>(
                x, cnt, bucket, A);
            gemm_mfma_kernel<IN_F, IN_F><<<NPAD / 64, 256, 0, stream>>>(
                A, BT, r * IN_F, out, h_bias, r == 0, r == N_REL - 1);
        }
    }
}